// Round 3
// baseline (692.115 us; speedup 1.0000x reference)
//
#include <hip/hip_runtime.h>
#include <hip/hip_bf16.h>

typedef __hip_bfloat16 bf16;
typedef __bf16 v8bf __attribute__((ext_vector_type(8)));
typedef float v4f __attribute__((ext_vector_type(4)));

#define PB 2304
#define PTOT 4608

__device__ __forceinline__ float b2f(bf16 x){ return __bfloat162float(x); }
__device__ __forceinline__ bf16 f2b(float x){ return __float2bfloat16(x); }
__device__ __forceinline__ float softplus_f(float x){
  return fmaxf(x, 0.f) + log1pf(expf(-fabsf(x)));
}
__device__ __forceinline__ float LD(const void* src, size_t i, int fl){
  return fl ? ((const float*)src)[i] : b2f(((const bf16*)src)[i]);
}

// async global->LDS DMA, 16B per lane; LDS dest is wave-uniform base + lane*16
__device__ __forceinline__ void gload_lds16(const void* g, void* l){
  __builtin_amdgcn_global_load_lds(
      (const __attribute__((address_space(1))) void*)g,
      (__attribute__((address_space(3))) void*)l, 16, 0, 0);
}

// ---------- dtype sniffer: flag=1 if float32, 0 if bf16 ----------
__global__ __launch_bounds__(256) void k_sniff(const unsigned* __restrict__ x, int* __restrict__ flag){
  int t = threadIdx.x;
  int cnt = 0;
  for (int i = t; i < 4096; i += 256){
    unsigned e = (x[i] >> 8) & 0x7F;
    if (e >= 0x38 && e <= 0x42) cnt++;
  }
  for (int off = 32; off; off >>= 1) cnt += __shfl_down(cnt, off, 64);
  __shared__ int sc[4];
  if ((t & 63) == 0) sc[t >> 6] = cnt;
  __syncthreads();
  if (t == 0) *flag = (sc[0]+sc[1]+sc[2]+sc[3] < 2048) ? 1 : 0;
}

__global__ void k_zero(float* __restrict__ p, int n){
  int i = blockIdx.x*256 + threadIdx.x;
  if (i < n) p[i] = 0.f;
}

// ---------- merged small-tensor canonicalization to f32 (SMALLF layout) ----------
__global__ __launch_bounds__(256) void k_cvt_small(
    const void* s4, const void* s10, const void* s16, const void* s6, const void* s8,
    const void* s12, const void* s14, const void* s18, const void* s20,
    const void* s21, const void* s22, const void* s23, const void* s24,
    const void* s25, const void* s26,
    float* __restrict__ dst, const int* __restrict__ flag){
  int i = blockIdx.x*256 + threadIdx.x;
  if (i >= 31321) return;
  int fl = *flag;
  const void* src; size_t off;
  if      (i < 128)   { src = s4;  off = i; }
  else if (i < 256)   { src = s10; off = i - 128; }
  else if (i < 384)   { src = s16; off = i - 256; }
  else if (i < 3456)  { src = s6;  off = i - 384; }
  else if (i < 6528)  { src = s8;  off = i - 3456; }
  else if (i < 6536)  { src = s12; off = i - 6528; }
  else if (i < 6544)  { src = s14; off = i - 6536; }
  else if (i < 6560)  { src = s18; off = i - 6544; }
  else if (i < 6576)  { src = s20; off = i - 6560; }
  else if (i < 31152) { src = s21; off = i - 6576; }
  else if (i < 31160) { src = s22; off = i - 31152; }
  else if (i < 31288) { src = s23; off = i - 31160; }
  else if (i < 31304) { src = s24; off = i - 31288; }
  else if (i < 31320) { src = s25; off = i - 31304; }
  else                { src = s26; off = i - 31320; }
  dst[i] = LD(src, off, fl);
}

// ---------- BCOL[64]: per-column biases for the small GEMMs ----------
__global__ __launch_bounds__(256) void k_bcol(const float* __restrict__ SMALLF, float* __restrict__ BCOL){
  int t = threadIdx.x;
  const float* BG1 = SMALLF + 6528; const float* BB1 = SMALLF + 6536;
  const float* BG2 = SMALLF + 6544; const float* BB2 = SMALLF + 6560;
  const float* BB0 = SMALLF + 3456; const float* W0  = SMALLF + 6576;
  if (t < 8)       BCOL[t] = BG1[t];
  else if (t < 16) BCOL[t] = BB1[t-8];
  else if (t < 32) BCOL[t] = BG2[t-16];
  else if (t < 48) BCOL[t] = BB2[t-32];
  else if (t < 64) BCOL[t] = 0.f;
  float part[8] = {0,0,0,0,0,0,0,0};
  for (int c = t; c < 3072; c += 256){
    float bb = BB0[c];
    #pragma unroll
    for (int oc = 0; oc < 8; oc++) part[oc] += bb*W0[oc*3072 + c];
  }
  __shared__ float red[4][8];
  int wv = t >> 6, lane = t & 63;
  #pragma unroll
  for (int oc = 0; oc < 8; oc++){
    float v = part[oc];
    for (int off = 32; off; off >>= 1) v += __shfl_down(v, off, 64);
    if (lane == 0) red[wv][oc] = v;
  }
  __syncthreads();
  if (t < 8) BCOL[48 + t] = red[0][t] + red[1][t] + red[2][t] + red[3][t];
}

__global__ __launch_bounds__(256) void k_mzero(float* __restrict__ MB){
  int i = blockIdx.x*256 + threadIdx.x;
  if (i < 9216) MB[i] = 0.f;
}

// ---------- M_beta[oc][j=dyx*128+ic] = sum_n wb0[n, ic, dyx] * w0[oc, n] ----------
__global__ __launch_bounds__(256) void k_mbeta(const void* __restrict__ wb0, const int* __restrict__ flag,
                                               const float* __restrict__ w0f, float* __restrict__ MB){
  int jb = blockIdx.x, nb = blockIdx.y, t = threadIdx.x;
  int fl = *flag;
  int jl = t & 127, nh = t >> 7;
  int j = jb*128 + jl;
  int src = jl*9 + jb;
  float acc[8] = {0,0,0,0,0,0,0,0};
  int n0 = nb*128 + nh*64;
  for (int i = 0; i < 64; i++){
    int n = n0 + i;
    float wv = LD(wb0, (size_t)n*1152 + src, fl);
    #pragma unroll
    for (int oc = 0; oc < 8; oc++) acc[oc] += wv*w0f[oc*3072 + n];
  }
  #pragma unroll
  for (int oc = 0; oc < 8; oc++) atomicAdd(&MB[oc*1152 + j], acc[oc]);
}

__global__ __launch_bounds__(256) void k_wsm(const float* __restrict__ MB, bf16* __restrict__ WSMALL){
  int i = blockIdx.x*256 + threadIdx.x;
  if (i >= 9216) return;
  float v = MB[i];
  bf16 hi = f2b(v);
  WSMALL[48*1152 + i] = hi;
  WSMALL[56*1152 + i] = f2b(v - b2f(hi));
}

// ---------- weight permute (oc, ic, 3,3) -> (oc, dyx, ic), bf16 out ----------
template<int ICW>
__global__ __launch_bounds__(256) void k_permW(const void* __restrict__ src, bf16* __restrict__ dst,
                                               int total, const int* __restrict__ flag){
  int idx = blockIdx.x*256 + threadIdx.x;
  if (idx >= total) return;
  int oc = idx / (9*ICW);
  int rr = idx % (9*ICW);
  int dyx = rr / ICW, ic = rr % ICW;
  size_t si = (size_t)(oc*ICW + ic)*9 + dyx;
  dst[idx] = f2b(LD(src, si, *flag));
}

// ---------- segment means over 24x24 downsampled segmap ----------
__global__ __launch_bounds__(256) void k_seg_means(const void* __restrict__ f_sem, const int* __restrict__ flag,
                                                   const int* __restrict__ segmap,
                                                   float* __restrict__ means){
  int s = blockIdx.x, b = blockIdx.y, t = threadIdx.x;
  int fl = *flag;
  __shared__ int sid[576];
  for (int i = t; i < 576; i += 256){
    int y = i / 24, x = i % 24;
    int v = segmap[b*336*336 + (y*14)*336 + x*14];
    sid[i] = min(max(v, 0), 63);
  }
  __syncthreads();
  float a0=0.f, a1=0.f, a2=0.f; int cnt = 0;
  for (int i = 0; i < 576; i++){
    if (sid[i] == s){
      cnt++;
      a0 += LD(f_sem, (size_t)(b*768 + t      )*576 + i, fl);
      a1 += LD(f_sem, (size_t)(b*768 + t + 256)*576 + i, fl);
      a2 += LD(f_sem, (size_t)(b*768 + t + 512)*576 + i, fl);
    }
  }
  float inv = cnt > 0 ? 1.f/(float)cnt : 0.f;
  float* o = means + (size_t)(b*64 + s)*768;
  o[t] = a0*inv; o[t+256] = a1*inv; o[t+512] = a2*inv;
}

// ---------- per-pixel segment weights (antialiased bilinear 336->48) ----------
__global__ __launch_bounds__(192) void k_A(const int* __restrict__ segmap, float* __restrict__ A){
  int blk = blockIdx.x;
  int b = blk / PB, rem = blk % PB, yo = rem / 48, xo = rem % 48;
  __shared__ float accs[64];
  int t = threadIdx.x;
  if (t < 64) accs[t] = 0.f;
  __syncthreads();
  if (t < 169){
    int ty = t / 13, tx = t % 13;
    int jy = 7*yo - 3 + ty, jx = 7*xo - 3 + tx;
    if (jy >= 0 && jy < 336 && jx >= 0 && jx < 336){
      int wy = 7 - abs(ty - 6), wx = 7 - abs(tx - 6);
      int sv = segmap[b*336*336 + jy*336 + jx];
      sv = min(max(sv, 0), 63);
      atomicAdd(&accs[sv], (float)(wy*wx));
    }
  }
  int sumy = 0, sumx = 0;
  for (int k = 0; k < 13; k++){
    int jy = 7*yo - 3 + k; if (jy >= 0 && jy < 336) sumy += 7 - abs(k - 6);
    int jx = 7*xo - 3 + k; if (jx >= 0 && jx < 336) sumx += 7 - abs(k - 6);
  }
  __syncthreads();
  if (t < 64) A[(size_t)blk*64 + t] = accs[t] / (float)(sumy*sumx);
}

// ---------- sem[p][c] = sum_s A[p][s]*means[b][s][c]  (bf16 out) ----------
__global__ __launch_bounds__(256) void k_sem(const float* __restrict__ A, const float* __restrict__ means,
                                             bf16* __restrict__ sem){
  int p = blockIdx.x, t = threadIdx.x;
  int b = p / PB;
  __shared__ float a[64];
  if (t < 64) a[t] = A[(size_t)p*64 + t];
  __syncthreads();
  const float* mb = means + (size_t)b*64*768;
  float a0=0.f, a1=0.f, a2=0.f;
  #pragma unroll 8
  for (int s = 0; s < 64; s++){
    float w = a[s];
    const float* mr = mb + s*768;
    a0 += w*mr[t]; a1 += w*mr[t+256]; a2 += w*mr[t+512];
  }
  bf16* o = sem + (size_t)p*768;
  o[t] = f2b(a0); o[t+256] = f2b(a1); o[t+512] = f2b(a2);
}

// ---------- LN stats over x_main ----------
__global__ __launch_bounds__(256) void k_ln_partial(const void* __restrict__ x, const int* __restrict__ flag,
                                                    float2* __restrict__ part){
  int b = blockIdx.y, blk = blockIdx.x, t = threadIdx.x;
  int fl = *flag;
  size_t base = (size_t)b*7077888 + (size_t)blk*55296;
  float s = 0.f, sq = 0.f;
  for (int i = 0; i < 216; i++){
    float v = LD(x, base + t + i*256, fl);
    s += v; sq += v*v;
  }
  for (int off = 32; off; off >>= 1){ s += __shfl_down(s, off, 64); sq += __shfl_down(sq, off, 64); }
  __shared__ float ls[4], lq[4];
  int w = t >> 6, lane = t & 63;
  if (lane == 0){ ls[w] = s; lq[w] = sq; }
  __syncthreads();
  if (t == 0) part[b*128 + blk] = make_float2(ls[0]+ls[1]+ls[2]+ls[3], lq[0]+lq[1]+lq[2]+lq[3]);
}

__global__ void k_ln_final(const float2* __restrict__ part, float* __restrict__ stats){
  int b = blockIdx.x, t = threadIdx.x;
  float2 v = part[b*128 + t];
  float s = v.x, sq = v.y;
  for (int off = 32; off; off >>= 1){ s += __shfl_down(s, off, 64); sq += __shfl_down(sq, off, 64); }
  __shared__ float ls[2], lq[2];
  if ((t & 63) == 0){ ls[t>>6] = s; lq[t>>6] = sq; }
  __syncthreads();
  if (t == 0){
    s = ls[0]+ls[1]; sq = lq[0]+lq[1];
    const float N = 7077888.f;
    float mean = s/N; float var = sq/N - mean*mean; var = fmaxf(var, 0.f);
    stats[b*2] = mean; stats[b*2+1] = rsqrtf(var + 1e-12f);
  }
}

__global__ __launch_bounds__(256) void k_ln_small(const float* __restrict__ z, int cnt, float* __restrict__ stats){
  int b = blockIdx.x, t = threadIdx.x;
  const float* p = z + (size_t)b*cnt;
  float s = 0.f, sq = 0.f;
  for (int i = t; i < cnt; i += 256){ float v = p[i]; s += v; sq += v*v; }
  for (int off = 32; off; off >>= 1){ s += __shfl_down(s, off, 64); sq += __shfl_down(sq, off, 64); }
  __shared__ float ls[4], lq[4];
  int w = t >> 6, lane = t & 63;
  if (lane == 0){ ls[w] = s; lq[w] = sq; }
  __syncthreads();
  if (t == 0){
    s = ls[0]+ls[1]+ls[2]+ls[3]; sq = lq[0]+lq[1]+lq[2]+lq[3];
    float mean = s/(float)cnt; float var = sq/(float)cnt - mean*mean; var = fmaxf(var, 0.f);
    stats[b*2] = mean; stats[b*2+1] = rsqrtf(var + 1e-12f);
  }
}

// ---------- MFMA GEMM (BK=64, 64x64 tile), LDS double-buffer + counted vmcnt ----------
// T3/T4 structure: prologue stages tile0; each iter issues tile kt+1's DMA into the
// other buffer then waits vmcnt(4) -- next-tile loads stay in flight across BOTH
// barriers; their latency hides under this tile's ds_read+MFMA. Tail drains vmcnt(0).
// Swizzle (seg ^ row&7) on global source + ds_read offsets, as in round 2.
template<bool RELU, typename OT>
__global__ __launch_bounds__(256) void k_gemm(
    const bf16* __restrict__ Asrc, int AS, int acol, int ICW,
    const bf16* __restrict__ W, int K,
    const float* __restrict__ bp0, const float* __restrict__ bp1, const float* __restrict__ bp2, int seg,
    OT* __restrict__ out, int N, int ncb, int ldo, const bf16* __restrict__ zpad)
{
  __shared__ __align__(16) bf16 Al[2][64][64];
  __shared__ __align__(16) bf16 Bl[2][64][64];
  int t = threadIdx.x;
  int m0 = blockIdx.x*64, n0 = blockIdx.y*64;
  int wv = t >> 6, lane = t & 63;
  int lr8 = lane >> 3, sseg = (lane & 7) ^ lr8;   // source 16B-seg (swizzled)
  int b = m0 >= PB ? 1 : 0;

  // per-lane row coords for the 2 DMA issues (rows wv*16 + i*8 + lr8)
  int ya[2], xa[2]; bool bv[2]; const bf16* wb[2];
  #pragma unroll
  for (int i = 0; i < 2; i++){
    int sp = (m0 - b*PB) + wv*16 + i*8 + lr8;
    ya[i] = sp / 48; xa[i] = sp % 48;
    int nrow = ncb + n0 + wv*16 + i*8 + lr8;
    bv[i] = nrow < N;
    wb[i] = W + (size_t)nrow*K + sseg*8;
  }

  int wm = (wv >> 1)*32, wn = (wv & 1)*32;
  int lrow = lane & 15, quad = lane >> 4;
  int sx = lrow & 7;
  int o0 = ((quad    ) ^ sx)*8;   // swizzled elem offset for K-seg quad
  int o1 = ((quad + 4) ^ sx)*8;   // and K-seg quad+4

  v4f acc00 = {0,0,0,0}, acc01 = {0,0,0,0}, acc10 = {0,0,0,0}, acc11 = {0,0,0,0};

  // incremental state for the NEXT tile to stage
  int dyxn = 0, icn = 0, kbn = 0;
  auto STAGE = [&](int buf){
    int dy = dyxn/3 - 1, dx = dyxn%3 - 1;
    #pragma unroll
    for (int i = 0; i < 2; i++){
      int ys = ya[i] + dy, xs = xa[i] + dx;
      const bf16* ga = (ys >= 0 && ys < 48 && xs >= 0 && xs < 48)
        ? Asrc + (size_t)(b*PB + ys*48 + xs)*AS + acol + icn + sseg*8 : zpad;
      gload_lds16(ga, &Al[buf][wv*16 + i*8][0]);
      const bf16* gb = bv[i] ? wb[i] + kbn : zpad;
      gload_lds16(gb, &Bl[buf][wv*16 + i*8][0]);
    }
    kbn += 64;
    icn += 64; if (icn == ICW){ icn = 0; dyxn++; }
  };

  int ktn = K / 64;
  STAGE(0);   // prologue: tile 0 -> buf 0
  for (int kt = 0; kt < ktn; kt++){
    int cur = kt & 1;
    if (kt + 1 < ktn){
      STAGE(cur ^ 1);                                      // tile kt+1 in flight
      asm volatile("s_waitcnt vmcnt(4)" ::: "memory");     // tile kt complete; kt+1 stays out
    } else {
      asm volatile("s_waitcnt vmcnt(0)" ::: "memory");
    }
    __builtin_amdgcn_sched_barrier(0);
    __syncthreads();
    const bf16 (*Ac)[64] = Al[cur];
    const bf16 (*Bc)[64] = Bl[cur];
    v8bf a00 = *reinterpret_cast<const v8bf*>(&Ac[wm      + lrow][o0]);
    v8bf a10 = *reinterpret_cast<const v8bf*>(&Ac[wm + 16 + lrow][o0]);
    v8bf a01 = *reinterpret_cast<const v8bf*>(&Ac[wm      + lrow][o1]);
    v8bf a11 = *reinterpret_cast<const v8bf*>(&Ac[wm + 16 + lrow][o1]);
    v8bf b00 = *reinterpret_cast<const v8bf*>(&Bc[wn      + lrow][o0]);
    v8bf b10 = *reinterpret_cast<const v8bf*>(&Bc[wn + 16 + lrow][o0]);
    v8bf b01 = *reinterpret_cast<const v8bf*>(&Bc[wn      + lrow][o1]);
    v8bf b11 = *reinterpret_cast<const v8bf*>(&Bc[wn + 16 + lrow][o1]);
    acc00 = __builtin_amdgcn_mfma_f32_16x16x32_bf16(a00, b00, acc00, 0, 0, 0);
    acc00 = __builtin_amdgcn_mfma_f32_16x16x32_bf16(a01, b01, acc00, 0, 0, 0);
    acc01 = __builtin_amdgcn_mfma_f32_16x16x32_bf16(a00, b10, acc01, 0, 0, 0);
    acc01 = __builtin_amdgcn_mfma_f32_16x16x32_bf16(a01, b11, acc01, 0, 0, 0);
    acc10 = __builtin_amdgcn_mfma_f32_16x16x32_bf16(a10, b00, acc10, 0, 0, 0);
    acc10 = __builtin_amdgcn_mfma_f32_16x16x32_bf16(a11, b01, acc10, 0, 0, 0);
    acc11 = __builtin_amdgcn_mfma_f32_16x16x32_bf16(a10, b10, acc11, 0, 0, 0);
    acc11 = __builtin_amdgcn_mfma_f32_16x16x32_bf16(a11, b11, acc11, 0, 0, 0);
    __syncthreads();   // protects buf[cur] from next iter's STAGE overwrite
  }

  auto store_tile = [&](v4f a, int mi, int ni){
    int gcol = ncb + n0 + wn + ni*16 + lrow;
    if (gcol >= N) return;
    int sel = gcol / seg; sel = sel > 2 ? 2 : sel;
    const float* bp = sel == 0 ? bp0 : (sel == 1 ? bp1 : bp2);
    float bias = bp[gcol - sel*seg];
    int rowb = m0 + wm + mi*16 + quad*4;
    #pragma unroll
    for (int rg = 0; rg < 4; rg++){
      float v = a[rg] + bias;
      if (RELU) v = fmaxf(v, 0.f);
      if constexpr (sizeof(OT) == 2) out[(size_t)(rowb+rg)*ldo + (gcol - ncb)] = f2b(v);
      else                           out[(size_t)(rowb+rg)*ldo + (gcol - ncb)] = (OT)v;
    }
  };
  store_tile(acc00, 0, 0); store_tile(acc01, 0, 1);
  store_tile(acc10, 1, 0); store_tile(acc11, 1, 1);
}

// ---------- fused gamma GEMM + z0 contraction (LDS double-buffer + counted vmcnt) ----------
// gamma[p,c] = im2col(HS,h0)[p,:]*WG0[c,:]^T + bg0[c]; z0[p,oc] += sum_c xn*(1+gamma)*w0[oc,c]
// grid (36, 24), block 256. tile 128p x 128c, BK=64, wave = 32p x 128c.
__global__ __launch_bounds__(256) void k_gfuse(
    const bf16* __restrict__ HS, const bf16* __restrict__ WG0, const float* __restrict__ BG0,
    const void* __restrict__ x, const int* __restrict__ flag, const float* __restrict__ stats,
    const float* __restrict__ w0f, float* __restrict__ z0, const bf16* __restrict__ zpad)
{
  __shared__ __align__(16) char lds_raw[65536];
  bf16 (*Al0)[64] = (bf16(*)[64])lds_raw;                  // [128][64] tile buf 0
  bf16 (*Bl0)[64] = (bf16(*)[64])(lds_raw + 16384);
  bf16 (*Al1)[64] = (bf16(*)[64])(lds_raw + 32768);        // [128][64] tile buf 1
  bf16 (*Bl1)[64] = (bf16(*)[64])(lds_raw + 49152);
  float (*xl)[132] = (float(*)[132])lds_raw;               // [64][132] epilogue reuse (33792 B)
  float (*w0l)[128] = (float(*)[128])(lds_raw + 33792);    // [8][128]
  float* bg0l = (float*)(lds_raw + 33792 + 4096);          // [128]

  int t = threadIdx.x;
  int m0 = blockIdx.x*128, n0 = blockIdx.y*128;
  int b = m0 >= PB ? 1 : 0;
  int fl = *flag;

  int wv = t >> 6, lane = t & 63;
  int lr8 = lane >> 3, sseg = (lane & 7) ^ lr8;   // swizzled source seg
  int spbase = m0 - b*PB;

  // per-lane pixel coords for the 4 A-row DMA issues (rows wv*32 + i*8 + lr8)
  int ya[4], xa[4];
  #pragma unroll
  for (int i = 0; i < 4; i++){
    int sp = spbase + wv*32 + i*8 + lr8;
    ya[i] = sp / 48; xa[i] = sp % 48;
  }
  const bf16* wgb = WG0 + (size_t)(n0 + wv*32 + lr8)*1152 + sseg*8;

  int wm = wv*32, lrow = lane & 15, quad = lane >> 4;
  int sx = lrow & 7;

  v4f acc[2][8];
  #pragma unroll
  for (int mi = 0; mi < 2; mi++)
    #pragma unroll
    for (int ni = 0; ni < 8; ni++) acc[mi][ni] = (v4f){0,0,0,0};

  auto STAGE = [&](int kt, bf16 (*Ad)[64], bf16 (*Bd)[64]){
    int dyx = kt >> 1, icr = (kt & 1) << 6;
    int dy = dyx/3 - 1, dx = dyx%3 - 1;
    #pragma unroll
    for (int i = 0; i < 4; i++){
      int ys = ya[i] + dy, xs = xa[i] + dx;
      const bf16* ga = (ys >= 0 && ys < 48 && xs >= 0 && xs < 48)
        ? HS + (size_t)(b*PB + ys*48 + xs)*384 + icr + sseg*8 : zpad;
      gload_lds16(ga, &Ad[wv*32 + i*8][0]);
      gload_lds16(wgb + (size_t)(i*8)*1152 + dyx*128 + icr, &Bd[wv*32 + i*8][0]);
    }
  };

  STAGE(0, Al0, Bl0);   // prologue: tile 0 -> buf 0
  for (int kt = 0; kt < 18; kt++){
    int cur = kt & 1;
    if (kt + 1 < 18){
      STAGE(kt + 1, cur ? Al0 : Al1, cur ? Bl0 : Bl1);     // next tile in flight
      asm volatile("s_waitcnt vmcnt(8)" ::: "memory");     // this tile complete
    } else {
      asm volatile("s_waitcnt vmcnt(0)" ::: "memory");
    }
    __builtin_amdgcn_sched_barrier(0);
    __syncthreads();
    const bf16 (*Ac)[64] = cur ? Al1 : Al0;
    const bf16 (*Bc)[64] = cur ? Bl1 : Bl0;
    #pragma unroll
    for (int kh = 0; kh < 2; kh++){
      int oa = ((kh*4 + quad) ^ sx)*8;   // swizzled elem offset
      v8bf a0 = *reinterpret_cast<const v8bf*>(&Ac[wm      + lrow][oa]);
      v8bf a1 = *reinterpret_cast<const v8bf*>(&Ac[wm + 16 + lrow][oa]);
      #pragma unroll
      for (int ni = 0; ni < 8; ni++){
        v8bf bn = *reinterpret_cast<const v8bf*>(&Bc[ni*16 + lrow][oa]);
        acc[0][ni] = __builtin_amdgcn_mfma_f32_16x16x32_bf16(a0, bn, acc[0][ni], 0, 0, 0);
        acc[1][ni] = __builtin_amdgcn_mfma_f32_16x16x32_bf16(a1, bn, acc[1][ni], 0, 0, 0);
      }
    }
    __syncthreads();   // protects buf[cur] before it is re-staged
  }

  // ---- epilogue: stage w0 slice + bg0 slice, then x tile in two 64-col halves ----
  for (int i = t; i < 1024; i += 256) w0l[i >> 7][i & 127] = w0f[(size_t)(i >> 7)*3072 + n0 + (i & 127)];
  if (t < 128) bg0l[t] = BG0[n0 + t];

  float mean = stats[b*2], rstd = stats[b*2+1];
  float s[2][4][8];
  #pragma unroll
  for (int mi = 0; mi < 2; mi++)
    #pragma unroll
    for (int rg = 0; rg < 4; rg++)
      #pragma unroll
      for (int oc = 0; oc < 8; oc++) s[mi][rg][oc] = 0.f;

  for (int h = 0; h < 2; h++){
    if (h) __syncthreads();
    // coalesced staging of x tile: 64 channels x 128 pixels
    if (fl){
      const float* xp = (const float*)x + ((size_t)(b*3072 + n0 + h*64))*2304 + spbase;
      #pragma unroll
      for (int it = 0; it < 8; it++){
        int idx = it*256 + t;
        int row = idx >> 5, c4 = (idx & 31)*4;
        float4 v = *reinterpret_cast<const float4*>(xp + (size_t)row*2304 + c4);
        *reinterpret_cast<float4*>(&xl[row][c4]) = v;
      }
    } else {
      const bf16* xp = (const bf16*)x + ((size_t)(b*3072 + n0 + h*64))*2304 + spbase;
      #pragma unroll
      for (int it = 0; it < 4; it++){
        int idx = it*256 + t;
        int row = idx >> 4, c8 = (idx & 15)*8;
        v8bf v = *reinterpret_cast<const v8bf*>(xp + (size_t)row*2304 + c8);
        float4 f0, f1;
        f0.x = (float)v[0]; f0.y = (float)v[1]; f0.z = (float)v[2]; f0.w = (float)v[3];
        f1.x = (float)v[4]; f1.y = (float)v[5]; f1.z = (float)v[6]; f1.w = (float)v[7];
        *reinterpret_cast<float4*>(&xl[row][c8])     = f0;
        *reinterpret_cast<float4*>(&xl[row][c8 + 4]) = f1;
      }
    }
    __syncthreads();
    #pragma unroll
    for (int mi = 0; mi < 2; mi++){
      int pl = wm + mi*16 + quad*4;
      #pragma unroll
      for (int nis = 0; nis < 4; nis++){
        int ni = h*4 + nis;
        int c_half = nis*16 + lrow;          // row in xl
        int c_blk = h*64 + c_half;           // block-local col
        float bg = bg0l[c_blk];
        float w0v[8];
        #pragma unroll
        for (int oc = 0; oc < 8; oc++) w0v[oc] = w0l[oc][c_blk];
        #pragma unroll
        for (int rg = 0; rg < 4; rg++){
          float gv = acc[mi][ni][rg] + bg;
          float xn = (xl[c_half][pl + rg] - mean)*rstd;
          float tv = xn*(1.f + gv);
          #pragma unroll
          for (int oc = 0; oc < 8; oc++) s[mi][rg][oc] += tv*w0v[oc];
        }
      }
    }
  }

  // reduce over the 16 lrow lanes (c within tile), then atomics
  #pragma unroll
  for (int mi = 0; mi < 2; mi++){
    #pragma unroll
    for (int rg = 0; rg < 4; rg++)
      #pragma unroll
      for (int oc = 0; oc < 8; oc++){
        float v = s[mi][rg][oc];
        v += __shfl_xor(v, 1, 64);
        v += __shfl_xor(v, 2, 64);
        v += __shfl_xor(v, 4, 64);
        v += __shfl_xor(v, 8, 64);
        s[mi][rg][oc] = v;
      }
    if (lrow == 0){
      int p = m0 + wm + mi*16 + quad*4;
      #pragma unroll
      for (int rg = 0; rg < 4; rg++)
        #pragma unroll
        for (int oc = 0; oc < 8; oc++)
          atomicAdd(&z0[(size_t)(p + rg)*8 + oc], s[mi][rg][oc]);
    }
  }
}

// ---------- z0 init: bias0 + beta-contraction (GBS cols 48..55 hi + 56..63 lo) ----------
__global__ __launch_bounds__(256) void k_z0init(const float* __restrict__ b0f, const float* __restrict__ GBS,
                                                float* __restrict__ z0){
  int i = blockIdx.x*256 + threadIdx.x;
  if (i >= 36864) return;
  int p = i >> 3, oc = i & 7;
  z0[i] = b0f[oc] + GBS[(size_t)p*64 + 48 + oc] + GBS[(size_t)p*64 + 56 + oc];
}

__global__ __launch_bounds__(256) void k_sp(float* z, int n){
  int i = blockIdx.x*256 + threadIdx.x;
  if (i < n) z[i] = softplus_f(z[i]);
}

__global__ __launch_bounds__(256) void k_F1(const float* __restrict__ z0, const float* __restrict__ GBS,
    const float* __restrict__ stats, const float* __restrict__ w1f, const float* __restrict__ b1f,
    float* __restrict__ z1){
  int p = blockIdx.x*256 + threadIdx.x;
  if (p >= PTOT) return;
  int b = p / PB;
  float mean = stats[b*2], rstd = stats[b*2+1];
  const float* zr = z0 + (size_t)p*8;
  const float* gr = GBS + (size_t)p*64;
  float yv[8];
  #pragma unroll
  for (int c = 0; c < 8; c++) yv[c] = (zr[c] - mean)*rstd*(1.f + gr[c]) + gr[8 + c];
  #pragma unroll
  for (int oc = 0; oc < 16; oc++){
    float s = b1f[oc];
    #pragma unroll
    for (int c = 0; c < 8; c++) s += yv[c]*w1f[oc*8 + c];
    z1[(size_t)p*16 + oc] = softplus_f(s);
  }
}

__global__ __launch_bounds__(256) void k_F2(const float* __restrict__ z1, const float* __restrict__ GBS,
    const float* __restrict__ stats, const float* __restrict__ w2f, const float* __restrict__ b2f,
    void* __restrict__ outp, const int* __restrict__ flag){
  int p = blockIdx.x*256 + threadIdx.x;
  if (p >= PTOT) return;
  int b = p / PB;
  float mean = stats[b*2], rstd = stats[b*2+1];
  const float* zr = z1 + (size_t)p*16;
  const float* gr = GBS + (size_t)p*64 + 16;
  float s = b2f[0];
  #pragma unroll
  for (int c = 0; c < 16; c++){
    float yv = (zr[c] - mean)*rstd*(1.f + gr[c]) + gr[16 + c];
    s += yv*w2f[c];
  }
  float r = softplus_f(s);
  if (*flag) ((float*)outp)[p] = r;
  else       ((bf16*)outp)[p] = f2b(r);
}

extern "C" void kernel_launch(void* const* d_in, const int* in_sizes, int n_in,
                              void* d_out, int out_size, void* d_ws, size_t ws_size,
                              hipStream_t stream){
  const void* x_main = d_in[0];
  const void* f_sem  = d_in[1];
  const int*  segmap = (const int*)d_in[2];

  char* ws = (char*)d_ws;
  size_t o = 0;
  auto alloc = [&](size_t bytes){ size_t r = o; o = (o + bytes + 255) & ~(size_t)255; return r; };
  float* MEANS = (float*)(ws + alloc(98304u*4));
  float* Amat  = (float*)(ws + alloc(294912u*4));
  bf16*  SEM   = (bf16*) (ws + alloc(3538944u*2));
  bf16*  WSC   = (bf16*) (ws + alloc(2654208u*2));
  bf16*  WG0   = (bf16*) (ws + alloc(3538944u*2));
  bf16*  WSMALL= (bf16*) (ws + alloc(73728u*2));
  bf16*  HS    = (bf16*) (ws + alloc(1769472u*2));
  float* GBS   = (float*)(ws + alloc(294912u*4));
  float* Z0    = (float*)(ws + alloc(36864u*4));
  float* Z1    = (float*)(ws + alloc(73728u*4));
  float2* LNP  = (float2*)(ws + alloc(256u*8));
  float* STATS = (float*)(ws + alloc(16u*4));
  int*   FLAG  = (int*)  (ws + alloc(64u));
  float* SMALLF= (float*)(ws + alloc(31321u*4));
  float* MB    = (float*)(ws + alloc(9216u*4));
  float* BCOL  = (float*)(ws + alloc(64u*4));
  bf16*  ZPAD  = (bf16*) (ws + alloc(512u));

  float *BS0=SMALLF+0, *BS1=SMALLF+128, *BS2=SMALLF+256;
  float *BG0=SMALLF+384;
  float *W0=SMALLF+6576, *B0=SMALLF+31152;
  float *W1=SMALLF+31160, *B1=SMALLF+31288;
  float *W2=SMALLF+31304, *B2=SMALLF+31320;

  k_sniff<<<1, 256, 0, stream>>>((const unsigned*)x_main, FLAG);
  k_zero<<<1, 256, 0, stream>>>((float*)ZPAD, 128);
  k_cvt_small<<<123, 256, 0, stream>>>(d_in[4], d_in[10], d_in[16], d_in[6], d_in[8],
      d_in[12], d_in[14], d_in[18], d_in[20], d_in[21], d_in[22], d_in[23], d_in[24],
      d_in[25], d_in[26], SMALLF, FLAG);
  k_bcol<<<1, 256, 0, stream>>>(SMALLF, BCOL);
  k_mzero<<<36, 256, 0, stream>>>(MB);
  k_mbeta<<<dim3(9,24), 256, 0, stream>>>(d_in[7], FLAG, W0, MB);
  k_wsm<<<36, 256, 0, stream>>>(MB, WSMALL);

  k_permW<768><<<dim3((884736+255)/256), 256, 0, stream>>>(d_in[3],  WSC,            884736, FLAG);
  k_permW<768><<<dim3((884736+255)/256), 256, 0, stream>>>(d_in[9],  WSC + 128*6912, 884736, FLAG);
  k_permW<768><<<dim3((884736+255)/256), 256, 0, stream>>>(d_in[15], WSC + 256*6912, 884736, FLAG);
  k_permW<128><<<dim3((3538944+255)/256),256, 0, stream>>>(d_in[5],  WG0,            3538944, FLAG);
  k_permW<128><<<dim3((9216+255)/256),   256, 0, stream>>>(d_in[11], WSMALL,           9216, FLAG);
  k_permW<128><<<dim3((9216+255)/256),   256, 0, stream>>>(d_in[13], WSMALL + 8*1152,  9216, FLAG);
  k_permW<128><<<dim3((18432+255)/256),  256, 0, stream>>>(d_in[17], WSMALL + 16*1152, 18432, FLAG);
  k_permW<128><<<dim3((18432+255)/256),  256, 0, stream>>>(d_in[19], WSMALL + 32*1152, 18432, FLAG);

  k_ln_partial<<<dim3(128,2), 256, 0, stream>>>(x_main, FLAG, LNP);
  k_ln_final<<<2, 128, 0, stream>>>(LNP, STATS);
  k_seg_means<<<dim3(64,2), 256, 0, stream>>>(f_sem, FLAG, segmap, MEANS);
  k_A<<<PTOT, 192, 0, stream>>>(segmap, Amat);
  k_sem<<<PTOT, 256, 0, stream>>>(Amat, MEANS, SEM);

  // G1: h = relu(conv3x3(sem, ws_l)) for all 3 layers -> HS (4608,384)
  k_gemm<true, bf16><<<dim3(72,6), 256, 0, stream>>>(SEM, 768, 0, 768, WSC, 6912,
      BS0, BS1, BS2, 128, HS, 384, 0, 384, ZPAD);
  // small GEMMs (per-layer A columns)
  k_gemm<false, float><<<dim3(72,1), 256, 0, stream>>>(HS, 384, 128, 128, WSMALL, 1152,
      BCOL, BCOL, BCOL, 9999, GBS, 16, 0, 64, ZPAD);
  k_gemm<false, float><<<dim3(72,1), 256, 0, stream>>>(HS, 384, 256, 128, WSMALL + 16*1152, 1152,
      BCOL+16, BCOL+16, BCOL+16, 9999, GBS+16, 32, 0, 64, ZPAD);
  k_gemm<false, float><<<dim3(72,1), 256, 0, stream>>>(HS, 384, 0, 128, WSMALL + 48*1152, 1152,
      BCOL+48, BCOL+48, BCOL+48, 9999, GBS+48, 16, 0, 64, ZPAD);

  // layer-0: z0 = bias0 + z0beta + sum_c xn*(1+gamma)*w0   (gamma fused, never materialized)
  k_z0init<<<144, 256, 0, stream>>>(B0, GBS, Z0);
  k_gfuse<<<dim3(36,24), 256, 0, stream>>>(HS, WG0, BG0, x_main, FLAG, STATS, W0, Z0, ZPAD);
  k_sp<<<144, 256, 0, stream>>>(Z0, 36864);

  k_ln_small<<<2, 256, 0, stream>>>(Z0, 18432, STATS + 4);
  k_F1<<<18, 256, 0, stream>>>(Z0, GBS, STATS + 4, W1, B1, Z1);
  k_ln_small<<<2, 256, 0, stream>>>(Z1, 36864, STATS + 8);
  k_F2<<<18, 256, 0, stream>>>(Z1, GBS, STATS + 8, W2, B2, d_out, FLAG);
}

// Round 4
// 634.461 us; speedup vs baseline: 1.0909x; 1.0909x over previous
//
#include <hip/hip_runtime.h>
#include <hip/hip_bf16.h>

typedef __hip_bfloat16 bf16;
typedef __bf16 v8bf __attribute__((ext_vector_type(8)));
typedef float v4f __attribute__((ext_vector_type(4)));

#define PB 2304
#define PTOT 4608

__device__ __forceinline__ float b2f(bf16 x){ return __bfloat162float(x); }
__device__ __forceinline__ bf16 f2b(float x){ return __float2bfloat16(x); }
__device__ __forceinline__ float softplus_f(float x){
  return fmaxf(x, 0.f) + log1pf(expf(-fabsf(x)));
}
__device__ __forceinline__ float LD(const void* src, size_t i, int fl){
  return fl ? ((const float*)src)[i] : b2f(((const bf16*)src)[i]);
}

// async global->LDS DMA, 16B per lane; LDS dest is wave-uniform base + lane*16
__device__ __forceinline__ void gload_lds16(const void* g, void* l){
  __builtin_amdgcn_global_load_lds(
      (const __attribute__((address_space(1))) void*)g,
      (__attribute__((address_space(3))) void*)l, 16, 0, 0);
}

// ---------- dtype sniffer: flag=1 if float32, 0 if bf16 ----------
__global__ __launch_bounds__(256) void k_sniff(const unsigned* __restrict__ x, int* __restrict__ flag){
  int t = threadIdx.x;
  int cnt = 0;
  for (int i = t; i < 4096; i += 256){
    unsigned e = (x[i] >> 8) & 0x7F;
    if (e >= 0x38 && e <= 0x42) cnt++;
  }
  for (int off = 32; off; off >>= 1) cnt += __shfl_down(cnt, off, 64);
  __shared__ int sc[4];
  if ((t & 63) == 0) sc[t >> 6] = cnt;
  __syncthreads();
  if (t == 0) *flag = (sc[0]+sc[1]+sc[2]+sc[3] < 2048) ? 1 : 0;
}

__global__ void k_zero(float* __restrict__ p, int n){
  int i = blockIdx.x*256 + threadIdx.x;
  if (i < n) p[i] = 0.f;
}

// ---------- merged small-tensor canonicalization to f32 (SMALLF layout) ----------
__global__ __launch_bounds__(256) void k_cvt_small(
    const void* s4, const void* s10, const void* s16, const void* s6, const void* s8,
    const void* s12, const void* s14, const void* s18, const void* s20,
    const void* s21, const void* s22, const void* s23, const void* s24,
    const void* s25, const void* s26,
    float* __restrict__ dst, const int* __restrict__ flag){
  int i = blockIdx.x*256 + threadIdx.x;
  if (i >= 31321) return;
  int fl = *flag;
  const void* src; size_t off;
  if      (i < 128)   { src = s4;  off = i; }
  else if (i < 256)   { src = s10; off = i - 128; }
  else if (i < 384)   { src = s16; off = i - 256; }
  else if (i < 3456)  { src = s6;  off = i - 384; }
  else if (i < 6528)  { src = s8;  off = i - 3456; }
  else if (i < 6536)  { src = s12; off = i - 6528; }
  else if (i < 6544)  { src = s14; off = i - 6536; }
  else if (i < 6560)  { src = s18; off = i - 6544; }
  else if (i < 6576)  { src = s20; off = i - 6560; }
  else if (i < 31152) { src = s21; off = i - 6576; }
  else if (i < 31160) { src = s22; off = i - 31152; }
  else if (i < 31288) { src = s23; off = i - 31160; }
  else if (i < 31304) { src = s24; off = i - 31288; }
  else if (i < 31320) { src = s25; off = i - 31304; }
  else                { src = s26; off = i - 31320; }
  dst[i] = LD(src, off, fl);
}

// ---------- BCOL[64]: per-column biases for the small GEMMs ----------
__global__ __launch_bounds__(256) void k_bcol(const float* __restrict__ SMALLF, float* __restrict__ BCOL){
  int t = threadIdx.x;
  const float* BG1 = SMALLF + 6528; const float* BB1 = SMALLF + 6536;
  const float* BG2 = SMALLF + 6544; const float* BB2 = SMALLF + 6560;
  const float* BB0 = SMALLF + 3456; const float* W0  = SMALLF + 6576;
  if (t < 8)       BCOL[t] = BG1[t];
  else if (t < 16) BCOL[t] = BB1[t-8];
  else if (t < 32) BCOL[t] = BG2[t-16];
  else if (t < 48) BCOL[t] = BB2[t-32];
  else if (t < 64) BCOL[t] = 0.f;
  float part[8] = {0,0,0,0,0,0,0,0};
  for (int c = t; c < 3072; c += 256){
    float bb = BB0[c];
    #pragma unroll
    for (int oc = 0; oc < 8; oc++) part[oc] += bb*W0[oc*3072 + c];
  }
  __shared__ float red[4][8];
  int wv = t >> 6, lane = t & 63;
  #pragma unroll
  for (int oc = 0; oc < 8; oc++){
    float v = part[oc];
    for (int off = 32; off; off >>= 1) v += __shfl_down(v, off, 64);
    if (lane == 0) red[wv][oc] = v;
  }
  __syncthreads();
  if (t < 8) BCOL[48 + t] = red[0][t] + red[1][t] + red[2][t] + red[3][t];
}

__global__ __launch_bounds__(256) void k_mzero(float* __restrict__ MB){
  int i = blockIdx.x*256 + threadIdx.x;
  if (i < 9216) MB[i] = 0.f;
}

// ---------- M_beta[oc][j=dyx*128+ic] = sum_n wb0[n, ic, dyx] * w0[oc, n] ----------
__global__ __launch_bounds__(256) void k_mbeta(const void* __restrict__ wb0, const int* __restrict__ flag,
                                               const float* __restrict__ w0f, float* __restrict__ MB){
  int jb = blockIdx.x, nb = blockIdx.y, t = threadIdx.x;
  int fl = *flag;
  int jl = t & 127, nh = t >> 7;
  int j = jb*128 + jl;
  int src = jl*9 + jb;
  float acc[8] = {0,0,0,0,0,0,0,0};
  int n0 = nb*128 + nh*64;
  for (int i = 0; i < 64; i++){
    int n = n0 + i;
    float wv = LD(wb0, (size_t)n*1152 + src, fl);
    #pragma unroll
    for (int oc = 0; oc < 8; oc++) acc[oc] += wv*w0f[oc*3072 + n];
  }
  #pragma unroll
  for (int oc = 0; oc < 8; oc++) atomicAdd(&MB[oc*1152 + j], acc[oc]);
}

__global__ __launch_bounds__(256) void k_wsm(const float* __restrict__ MB, bf16* __restrict__ WSMALL){
  int i = blockIdx.x*256 + threadIdx.x;
  if (i >= 9216) return;
  float v = MB[i];
  bf16 hi = f2b(v);
  WSMALL[48*1152 + i] = hi;
  WSMALL[56*1152 + i] = f2b(v - b2f(hi));
}

// ---------- weight permute (oc, ic, 3,3) -> (oc, dyx, ic), bf16 out ----------
template<int ICW>
__global__ __launch_bounds__(256) void k_permW(const void* __restrict__ src, bf16* __restrict__ dst,
                                               int total, const int* __restrict__ flag){
  int idx = blockIdx.x*256 + threadIdx.x;
  if (idx >= total) return;
  int oc = idx / (9*ICW);
  int rr = idx % (9*ICW);
  int dyx = rr / ICW, ic = rr % ICW;
  size_t si = (size_t)(oc*ICW + ic)*9 + dyx;
  dst[idx] = f2b(LD(src, si, *flag));
}

// ---------- segment means over 24x24 downsampled segmap ----------
__global__ __launch_bounds__(256) void k_seg_means(const void* __restrict__ f_sem, const int* __restrict__ flag,
                                                   const int* __restrict__ segmap,
                                                   float* __restrict__ means){
  int s = blockIdx.x, b = blockIdx.y, t = threadIdx.x;
  int fl = *flag;
  __shared__ int sid[576];
  for (int i = t; i < 576; i += 256){
    int y = i / 24, x = i % 24;
    int v = segmap[b*336*336 + (y*14)*336 + x*14];
    sid[i] = min(max(v, 0), 63);
  }
  __syncthreads();
  float a0=0.f, a1=0.f, a2=0.f; int cnt = 0;
  for (int i = 0; i < 576; i++){
    if (sid[i] == s){
      cnt++;
      a0 += LD(f_sem, (size_t)(b*768 + t      )*576 + i, fl);
      a1 += LD(f_sem, (size_t)(b*768 + t + 256)*576 + i, fl);
      a2 += LD(f_sem, (size_t)(b*768 + t + 512)*576 + i, fl);
    }
  }
  float inv = cnt > 0 ? 1.f/(float)cnt : 0.f;
  float* o = means + (size_t)(b*64 + s)*768;
  o[t] = a0*inv; o[t+256] = a1*inv; o[t+512] = a2*inv;
}

// ---------- TT[b][oc][dyx][s] = sum_ic ws_l[oc][ic][dyx] * means[b][s][ic] ----------
// Folds means into conv weights: h_pre[p,oc] = sum_{dyx,s} A[p+dyx,s]*TT (the conv over
// sem=A*means is linear, so SEM never needs materializing and G1's K drops 6912->1152).
// Layout: WTT[(b*384+oc)*1152 + dyx*128 + s] with both 64-halves duplicated (A hi/lo split).
// grid (216 = dyx*24 + ocb, 2 batches), block 256. Each block: 16 oc x 1 dyx x 64 s.
__global__ __launch_bounds__(256) void k_tt(const void* __restrict__ ws0, const void* __restrict__ ws1,
    const void* __restrict__ ws2, const int* __restrict__ flag,
    const float* __restrict__ means, bf16* __restrict__ WTT){
  int bx = blockIdx.x;
  int dyx = bx / 24, ocb = bx % 24;
  int b = blockIdx.y, t = threadIdx.x;
  int fl = *flag;
  int ocg0 = ocb*16;
  const void* wsrc; int ocl0 = ocg0;
  if (ocl0 < 128) wsrc = ws0;
  else if (ocl0 < 256){ wsrc = ws1; ocl0 -= 128; }
  else { wsrc = ws2; ocl0 -= 256; }
  __shared__ float wl[16][768];
  for (int ol = 0; ol < 16; ol++)
    for (int ic = t; ic < 768; ic += 256)
      wl[ol][ic] = LD(wsrc, (size_t)(ocl0 + ol)*6912 + (size_t)ic*9 + dyx, fl);
  __syncthreads();
  int s = t & 63, og = t >> 6;   // og = wave id: wl reads broadcast within wave
  const float* mr = means + ((size_t)b*64 + s)*768;
  float acc[4] = {0.f, 0.f, 0.f, 0.f};
  for (int ic = 0; ic < 768; ic += 4){
    float4 m = *reinterpret_cast<const float4*>(mr + ic);
    #pragma unroll
    for (int k = 0; k < 4; k++){
      const float* w = &wl[og + k*4][ic];
      acc[k] += m.x*w[0] + m.y*w[1] + m.z*w[2] + m.w*w[3];
    }
  }
  #pragma unroll
  for (int k = 0; k < 4; k++){
    bf16 h = f2b(acc[k]);
    size_t base = ((size_t)(b*384 + ocg0 + og + k*4))*1152 + (size_t)dyx*128 + s;
    WTT[base] = h;
    WTT[base + 64] = h;
  }
}

// ---------- per-pixel segment weights (antialiased bilinear 336->48), bf16 hi/lo out ----------
// AHL[pix*128 + s] = bf16_hi(A[pix][s]); AHL[pix*128 + 64 + s] = bf16 residual.
__global__ __launch_bounds__(192) void k_A(const int* __restrict__ segmap, bf16* __restrict__ AHL){
  int blk = blockIdx.x;
  int b = blk / PB, rem = blk % PB, yo = rem / 48, xo = rem % 48;
  __shared__ float accs[64];
  int t = threadIdx.x;
  if (t < 64) accs[t] = 0.f;
  __syncthreads();
  if (t < 169){
    int ty = t / 13, tx = t % 13;
    int jy = 7*yo - 3 + ty, jx = 7*xo - 3 + tx;
    if (jy >= 0 && jy < 336 && jx >= 0 && jx < 336){
      int wy = 7 - abs(ty - 6), wx = 7 - abs(tx - 6);
      int sv = segmap[b*336*336 + jy*336 + jx];
      sv = min(max(sv, 0), 63);
      atomicAdd(&accs[sv], (float)(wy*wx));
    }
  }
  int sumy = 0, sumx = 0;
  for (int k = 0; k < 13; k++){
    int jy = 7*yo - 3 + k; if (jy >= 0 && jy < 336) sumy += 7 - abs(k - 6);
    int jx = 7*xo - 3 + k; if (jx >= 0 && jx < 336) sumx += 7 - abs(k - 6);
  }
  __syncthreads();
  if (t < 64){
    float v = accs[t] / (float)(sumy*sumx);
    bf16 hi = f2b(v);
    AHL[(size_t)blk*128 + t] = hi;
    AHL[(size_t)blk*128 + 64 + t] = f2b(v - b2f(hi));
  }
}

// ---------- LN stats over x_main ----------
__global__ __launch_bounds__(256) void k_ln_partial(const void* __restrict__ x, const int* __restrict__ flag,
                                                    float2* __restrict__ part){
  int b = blockIdx.y, blk = blockIdx.x, t = threadIdx.x;
  int fl = *flag;
  size_t base = (size_t)b*7077888 + (size_t)blk*55296;
  float s = 0.f, sq = 0.f;
  for (int i = 0; i < 216; i++){
    float v = LD(x, base + t + i*256, fl);
    s += v; sq += v*v;
  }
  for (int off = 32; off; off >>= 1){ s += __shfl_down(s, off, 64); sq += __shfl_down(sq, off, 64); }
  __shared__ float ls[4], lq[4];
  int w = t >> 6, lane = t & 63;
  if (lane == 0){ ls[w] = s; lq[w] = sq; }
  __syncthreads();
  if (t == 0) part[b*128 + blk] = make_float2(ls[0]+ls[1]+ls[2]+ls[3], lq[0]+lq[1]+lq[2]+lq[3]);
}

__global__ void k_ln_final(const float2* __restrict__ part, float* __restrict__ stats){
  int b = blockIdx.x, t = threadIdx.x;
  float2 v = part[b*128 + t];
  float s = v.x, sq = v.y;
  for (int off = 32; off; off >>= 1){ s += __shfl_down(s, off, 64); sq += __shfl_down(sq, off, 64); }
  __shared__ float ls[2], lq[2];
  if ((t & 63) == 0){ ls[t>>6] = s; lq[t>>6] = sq; }
  __syncthreads();
  if (t == 0){
    s = ls[0]+ls[1]; sq = lq[0]+lq[1];
    const float N = 7077888.f;
    float mean = s/N; float var = sq/N - mean*mean; var = fmaxf(var, 0.f);
    stats[b*2] = mean; stats[b*2+1] = rsqrtf(var + 1e-12f);
  }
}

__global__ __launch_bounds__(256) void k_ln_small(const float* __restrict__ z, int cnt, float* __restrict__ stats){
  int b = blockIdx.x, t = threadIdx.x;
  const float* p = z + (size_t)b*cnt;
  float s = 0.f, sq = 0.f;
  for (int i = t; i < cnt; i += 256){ float v = p[i]; s += v; sq += v*v; }
  for (int off = 32; off; off >>= 1){ s += __shfl_down(s, off, 64); sq += __shfl_down(sq, off, 64); }
  __shared__ float ls[4], lq[4];
  int w = t >> 6, lane = t & 63;
  if (lane == 0){ ls[w] = s; lq[w] = sq; }
  __syncthreads();
  if (t == 0){
    s = ls[0]+ls[1]+ls[2]+ls[3]; sq = lq[0]+lq[1]+lq[2]+lq[3];
    float mean = s/(float)cnt; float var = sq/(float)cnt - mean*mean; var = fmaxf(var, 0.f);
    stats[b*2] = mean; stats[b*2+1] = rsqrtf(var + 1e-12f);
  }
}

// ---------- MFMA GEMM (BK=64, 64x64 tile) via async global_load_lds staging ----------
// m97 2-barrier structure (round-2 measured best): DMA stage -> vmcnt(0)+barrier ->
// ds_read+MFMA -> barrier. Linear LDS [64][64] bf16; 16B-seg XOR swizzle on global
// source AND ds_read offsets. OOB lanes use the zeroed guard page.
// W may be batch-dependent (wbstride = per-batch element stride, 0 if shared).
template<bool RELU, typename OT>
__global__ __launch_bounds__(256) void k_gemm(
    const bf16* __restrict__ Asrc, int AS, int acol, int ICW,
    const bf16* __restrict__ W, int K, size_t wbstride,
    const float* __restrict__ bp0, const float* __restrict__ bp1, const float* __restrict__ bp2, int seg,
    OT* __restrict__ out, int N, int ncb, int ldo, const bf16* __restrict__ zpad)
{
  __shared__ __align__(16) bf16 Al[64][64];
  __shared__ __align__(16) bf16 Bl[64][64];
  int t = threadIdx.x;
  int m0 = blockIdx.x*64, n0 = blockIdx.y*64;
  int wv = t >> 6, lane = t & 63;
  int lr8 = lane >> 3, sseg = (lane & 7) ^ lr8;   // source 16B-seg (swizzled)
  int b = m0 >= PB ? 1 : 0;

  // per-lane row coords for the 2 DMA issues (rows wv*16 + i*8 + lr8)
  int ya[2], xa[2]; bool bv[2]; const bf16* wb[2];
  #pragma unroll
  for (int i = 0; i < 2; i++){
    int sp = (m0 - b*PB) + wv*16 + i*8 + lr8;
    ya[i] = sp / 48; xa[i] = sp % 48;
    int nrow = ncb + n0 + wv*16 + i*8 + lr8;
    bv[i] = nrow < N;
    wb[i] = W + (size_t)b*wbstride + (size_t)nrow*K + sseg*8;
  }

  int wm = (wv >> 1)*32, wn = (wv & 1)*32;
  int lrow = lane & 15, quad = lane >> 4;
  int sx = lrow & 7;
  int o0 = ((quad    ) ^ sx)*8;   // swizzled elem offset for K-seg quad
  int o1 = ((quad + 4) ^ sx)*8;   // and K-seg quad+4

  v4f acc00 = {0,0,0,0}, acc01 = {0,0,0,0}, acc10 = {0,0,0,0}, acc11 = {0,0,0,0};

  int dyx = 0, ic0 = 0;
  int ktn = K / 64;
  for (int kt = 0; kt < ktn; kt++){
    int dy = dyx/3 - 1, dx = dyx%3 - 1;
    #pragma unroll
    for (int i = 0; i < 2; i++){
      int ys = ya[i] + dy, xs = xa[i] + dx;
      const bf16* ga = (ys >= 0 && ys < 48 && xs >= 0 && xs < 48)
        ? Asrc + (size_t)(b*PB + ys*48 + xs)*AS + acol + ic0 + sseg*8 : zpad;
      gload_lds16(ga, &Al[wv*16 + i*8][0]);
      const bf16* gb = bv[i] ? wb[i] + kt*64 : zpad;
      gload_lds16(gb, &Bl[wv*16 + i*8][0]);
    }
    asm volatile("s_waitcnt vmcnt(0)" ::: "memory");
    __syncthreads();
    v8bf a00 = *reinterpret_cast<const v8bf*>(&Al[wm      + lrow][o0]);
    v8bf a10 = *reinterpret_cast<const v8bf*>(&Al[wm + 16 + lrow][o0]);
    v8bf a01 = *reinterpret_cast<const v8bf*>(&Al[wm      + lrow][o1]);
    v8bf a11 = *reinterpret_cast<const v8bf*>(&Al[wm + 16 + lrow][o1]);
    v8bf b00 = *reinterpret_cast<const v8bf*>(&Bl[wn      + lrow][o0]);
    v8bf b10 = *reinterpret_cast<const v8bf*>(&Bl[wn + 16 + lrow][o0]);
    v8bf b01 = *reinterpret_cast<const v8bf*>(&Bl[wn      + lrow][o1]);
    v8bf b11 = *reinterpret_cast<const v8bf*>(&Bl[wn + 16 + lrow][o1]);
    acc00 = __builtin_amdgcn_mfma_f32_16x16x32_bf16(a00, b00, acc00, 0, 0, 0);
    acc00 = __builtin_amdgcn_mfma_f32_16x16x32_bf16(a01, b01, acc00, 0, 0, 0);
    acc01 = __builtin_amdgcn_mfma_f32_16x16x32_bf16(a00, b10, acc01, 0, 0, 0);
    acc01 = __builtin_amdgcn_mfma_f32_16x16x32_bf16(a01, b11, acc01, 0, 0, 0);
    acc10 = __builtin_amdgcn_mfma_f32_16x16x32_bf16(a10, b00, acc10, 0, 0, 0);
    acc10 = __builtin_amdgcn_mfma_f32_16x16x32_bf16(a11, b01, acc10, 0, 0, 0);
    acc11 = __builtin_amdgcn_mfma_f32_16x16x32_bf16(a10, b10, acc11, 0, 0, 0);
    acc11 = __builtin_amdgcn_mfma_f32_16x16x32_bf16(a11, b11, acc11, 0, 0, 0);
    __syncthreads();
    ic0 += 64; if (ic0 == ICW){ ic0 = 0; dyx++; }
  }

  auto store_tile = [&](v4f a, int mi, int ni){
    int gcol = ncb + n0 + wn + ni*16 + lrow;
    if (gcol >= N) return;
    int sel = gcol / seg; sel = sel > 2 ? 2 : sel;
    const float* bp = sel == 0 ? bp0 : (sel == 1 ? bp1 : bp2);
    float bias = bp[gcol - sel*seg];
    int rowb = m0 + wm + mi*16 + quad*4;
    #pragma unroll
    for (int rg = 0; rg < 4; rg++){
      float v = a[rg] + bias;
      if (RELU) v = fmaxf(v, 0.f);
      if constexpr (sizeof(OT) == 2) out[(size_t)(rowb+rg)*ldo + (gcol - ncb)] = f2b(v);
      else                           out[(size_t)(rowb+rg)*ldo + (gcol - ncb)] = (OT)v;
    }
  };
  store_tile(acc00, 0, 0); store_tile(acc01, 0, 1);
  store_tile(acc10, 1, 0); store_tile(acc11, 1, 1);
}

// ---------- fused gamma GEMM + z0 contraction (async global_load_lds staging) ----------
// gamma[p,c] = im2col(HS,h0)[p,:]*WG0[c,:]^T + bg0[c]; z0[p,oc] += sum_c xn*(1+gamma)*w0[oc,c]
// grid (36, 24), block 256. tile 128p x 128c, BK=64, wave = 32p x 128c.
__global__ __launch_bounds__(256) void k_gfuse(
    const bf16* __restrict__ HS, const bf16* __restrict__ WG0, const float* __restrict__ BG0,
    const void* __restrict__ x, const int* __restrict__ flag, const float* __restrict__ stats,
    const float* __restrict__ w0f, float* __restrict__ z0, const bf16* __restrict__ zpad)
{
  __shared__ __align__(16) char lds_raw[38912];
  bf16 (*Al)[64]  = (bf16(*)[64])lds_raw;                  // [128][64] linear (DMA dest)
  bf16 (*Bl)[64]  = (bf16(*)[64])(lds_raw + 16384);        // [128][64] linear (DMA dest)
  float (*xl)[132] = (float(*)[132])lds_raw;               // [64][132] (reuse, 33792 B)
  float (*w0l)[128] = (float(*)[128])(lds_raw + 33792);    // [8][128]
  float* bg0l = (float*)(lds_raw + 33792 + 4096);          // [128]

  int t = threadIdx.x;
  int m0 = blockIdx.x*128, n0 = blockIdx.y*128;
  int b = m0 >= PB ? 1 : 0;
  int fl = *flag;

  int wv = t >> 6, lane = t & 63;
  int lr8 = lane >> 3, sseg = (lane & 7) ^ lr8;   // swizzled source seg
  int spbase = m0 - b*PB;

  // per-lane pixel coords for the 4 A-row DMA issues (rows wv*32 + i*8 + lr8)
  int ya[4], xa[4];
  #pragma unroll
  for (int i = 0; i < 4; i++){
    int sp = spbase + wv*32 + i*8 + lr8;
    ya[i] = sp / 48; xa[i] = sp % 48;
  }
  const bf16* wgb = WG0 + (size_t)(n0 + wv*32 + lr8)*1152 + sseg*8;

  int wm = wv*32, lrow = lane & 15, quad = lane >> 4;
  int sx = lrow & 7;

  v4f acc[2][8];
  #pragma unroll
  for (int mi = 0; mi < 2; mi++)
    #pragma unroll
    for (int ni = 0; ni < 8; ni++) acc[mi][ni] = (v4f){0,0,0,0};

  for (int kt = 0; kt < 18; kt++){
    int dyx = kt >> 1, icr = (kt & 1) << 6;
    int dy = dyx/3 - 1, dx = dyx%3 - 1;
    #pragma unroll
    for (int i = 0; i < 4; i++){
      int ys = ya[i] + dy, xs = xa[i] + dx;
      const bf16* ga = (ys >= 0 && ys < 48 && xs >= 0 && xs < 48)
        ? HS + (size_t)(b*PB + ys*48 + xs)*384 + icr + sseg*8 : zpad;
      gload_lds16(ga, &Al[wv*32 + i*8][0]);
      gload_lds16(wgb + (size_t)(i*8)*1152 + dyx*128 + icr, &Bl[wv*32 + i*8][0]);
    }
    asm volatile("s_waitcnt vmcnt(0)" ::: "memory");
    __syncthreads();
    #pragma unroll
    for (int kh = 0; kh < 2; kh++){
      int oa = ((kh*4 + quad) ^ sx)*8;   // swizzled elem offset
      v8bf a0 = *reinterpret_cast<const v8bf*>(&Al[wm      + lrow][oa]);
      v8bf a1 = *reinterpret_cast<const v8bf*>(&Al[wm + 16 + lrow][oa]);
      #pragma unroll
      for (int ni = 0; ni < 8; ni++){
        v8bf bn = *reinterpret_cast<const v8bf*>(&Bl[ni*16 + lrow][oa]);
        acc[0][ni] = __builtin_amdgcn_mfma_f32_16x16x32_bf16(a0, bn, acc[0][ni], 0, 0, 0);
        acc[1][ni] = __builtin_amdgcn_mfma_f32_16x16x32_bf16(a1, bn, acc[1][ni], 0, 0, 0);
      }
    }
    __syncthreads();
  }

  // ---- epilogue: stage w0 slice + bg0 slice, then x tile in two 64-col halves ----
  for (int i = t; i < 1024; i += 256) w0l[i >> 7][i & 127] = w0f[(size_t)(i >> 7)*3072 + n0 + (i & 127)];
  if (t < 128) bg0l[t] = BG0[n0 + t];

  float mean = stats[b*2], rstd = stats[b*2+1];
  float s[2][4][8];
  #pragma unroll
  for (int mi = 0; mi < 2; mi++)
    #pragma unroll
    for (int rg = 0; rg < 4; rg++)
      #pragma unroll
      for (int oc = 0; oc < 8; oc++) s[mi][rg][oc] = 0.f;

  for (int h = 0; h < 2; h++){
    if (h) __syncthreads();
    // coalesced staging of x tile: 64 channels x 128 pixels
    if (fl){
      const float* xp = (const float*)x + ((size_t)(b*3072 + n0 + h*64))*2304 + spbase;
      #pragma unroll
      for (int it = 0; it < 8; it++){
        int idx = it*256 + t;
        int row = idx >> 5, c4 = (idx & 31)*4;
        float4 v = *reinterpret_cast<const float4*>(xp + (size_t)row*2304 + c4);
        *reinterpret_cast<float4*>(&xl[row][c4]) = v;
      }
    } else {
      const bf16* xp = (const bf16*)x + ((size_t)(b*3072 + n0 + h*64))*2304 + spbase;
      #pragma unroll
      for (int it = 0; it < 4; it++){
        int idx = it*256 + t;
        int row = idx >> 4, c8 = (idx & 15)*8;
        v8bf v = *reinterpret_cast<const v8bf*>(xp + (size_t)row*2304 + c8);
        float4 f0, f1;
        f0.x = (float)v[0]; f0.y = (float)v[1]; f0.z = (float)v[2]; f0.w = (float)v[3];
        f1.x = (float)v[4]; f1.y = (float)v[5]; f1.z = (float)v[6]; f1.w = (float)v[7];
        *reinterpret_cast<float4*>(&xl[row][c8])     = f0;
        *reinterpret_cast<float4*>(&xl[row][c8 + 4]) = f1;
      }
    }
    __syncthreads();
    #pragma unroll
    for (int mi = 0; mi < 2; mi++){
      int pl = wm + mi*16 + quad*4;
      #pragma unroll
      for (int nis = 0; nis < 4; nis++){
        int ni = h*4 + nis;
        int c_half = nis*16 + lrow;          // row in xl
        int c_blk = h*64 + c_half;           // block-local col
        float bg = bg0l[c_blk];
        float w0v[8];
        #pragma unroll
        for (int oc = 0; oc < 8; oc++) w0v[oc] = w0l[oc][c_blk];
        #pragma unroll
        for (int rg = 0; rg < 4; rg++){
          float gv = acc[mi][ni][rg] + bg;
          float xn = (xl[c_half][pl + rg] - mean)*rstd;
          float tv = xn*(1.f + gv);
          #pragma unroll
          for (int oc = 0; oc < 8; oc++) s[mi][rg][oc] += tv*w0v[oc];
        }
      }
    }
  }

  // reduce over the 16 lrow lanes (c within tile), then atomics
  #pragma unroll
  for (int mi = 0; mi < 2; mi++){
    #pragma unroll
    for (int rg = 0; rg < 4; rg++)
      #pragma unroll
      for (int oc = 0; oc < 8; oc++){
        float v = s[mi][rg][oc];
        v += __shfl_xor(v, 1, 64);
        v += __shfl_xor(v, 2, 64);
        v += __shfl_xor(v, 4, 64);
        v += __shfl_xor(v, 8, 64);
        s[mi][rg][oc] = v;
      }
    if (lrow == 0){
      int p = m0 + wm + mi*16 + quad*4;
      #pragma unroll
      for (int rg = 0; rg < 4; rg++)
        #pragma unroll
        for (int oc = 0; oc < 8; oc++)
          atomicAdd(&z0[(size_t)(p + rg)*8 + oc], s[mi][rg][oc]);
    }
  }
}

// ---------- z0 init: bias0 + beta-contraction (GBS cols 48..55 hi + 56..63 lo) ----------
__global__ __launch_bounds__(256) void k_z0init(const float* __restrict__ b0f, const float* __restrict__ GBS,
                                                float* __restrict__ z0){
  int i = blockIdx.x*256 + threadIdx.x;
  if (i >= 36864) return;
  int p = i >> 3, oc = i & 7;
  z0[i] = b0f[oc] + GBS[(size_t)p*64 + 48 + oc] + GBS[(size_t)p*64 + 56 + oc];
}

__global__ __launch_bounds__(256) void k_sp(float* z, int n){
  int i = blockIdx.x*256 + threadIdx.x;
  if (i < n) z[i] = softplus_f(z[i]);
}

__global__ __launch_bounds__(256) void k_F1(const float* __restrict__ z0, const float* __restrict__ GBS,
    const float* __restrict__ stats, const float* __restrict__ w1f, const float* __restrict__ b1f,
    float* __restrict__ z1){
  int p = blockIdx.x*256 + threadIdx.x;
  if (p >= PTOT) return;
  int b = p / PB;
  float mean = stats[b*2], rstd = stats[b*2+1];
  const float* zr = z0 + (size_t)p*8;
  const float* gr = GBS + (size_t)p*64;
  float yv[8];
  #pragma unroll
  for (int c = 0; c < 8; c++) yv[c] = (zr[c] - mean)*rstd*(1.f + gr[c]) + gr[8 + c];
  #pragma unroll
  for (int oc = 0; oc < 16; oc++){
    float s = b1f[oc];
    #pragma unroll
    for (int c = 0; c < 8; c++) s += yv[c]*w1f[oc*8 + c];
    z1[(size_t)p*16 + oc] = softplus_f(s);
  }
}

__global__ __launch_bounds__(256) void k_F2(const float* __restrict__ z1, const float* __restrict__ GBS,
    const float* __restrict__ stats, const float* __restrict__ w2f, const float* __restrict__ b2f,
    void* __restrict__ outp, const int* __restrict__ flag){
  int p = blockIdx.x*256 + threadIdx.x;
  if (p >= PTOT) return;
  int b = p / PB;
  float mean = stats[b*2], rstd = stats[b*2+1];
  const float* zr = z1 + (size_t)p*16;
  const float* gr = GBS + (size_t)p*64 + 16;
  float s = b2f[0];
  #pragma unroll
  for (int c = 0; c < 16; c++){
    float yv = (zr[c] - mean)*rstd*(1.f + gr[c]) + gr[16 + c];
    s += yv*w2f[c];
  }
  float r = softplus_f(s);
  if (*flag) ((float*)outp)[p] = r;
  else       ((bf16*)outp)[p] = f2b(r);
}

extern "C" void kernel_launch(void* const* d_in, const int* in_sizes, int n_in,
                              void* d_out, int out_size, void* d_ws, size_t ws_size,
                              hipStream_t stream){
  const void* x_main = d_in[0];
  const void* f_sem  = d_in[1];
  const int*  segmap = (const int*)d_in[2];

  char* ws = (char*)d_ws;
  size_t o = 0;
  auto alloc = [&](size_t bytes){ size_t r = o; o = (o + bytes + 255) & ~(size_t)255; return r; };
  float* MEANS = (float*)(ws + alloc(98304u*4));
  bf16*  AHL   = (bf16*) (ws + alloc(589824u*2));    // PTOT*128 hi/lo A weights
  bf16*  WTT   = (bf16*) (ws + alloc(884736u*2));    // 2*384*1152 folded conv weights
  bf16*  WG0   = (bf16*) (ws + alloc(3538944u*2));
  bf16*  WSMALL= (bf16*) (ws + alloc(73728u*2));
  bf16*  HS    = (bf16*) (ws + alloc(1769472u*2));
  float* GBS   = (float*)(ws + alloc(294912u*4));
  float* Z0    = (float*)(ws + alloc(36864u*4));
  float* Z1    = (float*)(ws + alloc(73728u*4));
  float2* LNP  = (float2*)(ws + alloc(256u*8));
  float* STATS = (float*)(ws + alloc(16u*4));
  int*   FLAG  = (int*)  (ws + alloc(64u));
  float* SMALLF= (float*)(ws + alloc(31321u*4));
  float* MB    = (float*)(ws + alloc(9216u*4));
  float* BCOL  = (float*)(ws + alloc(64u*4));
  bf16*  ZPAD  = (bf16*) (ws + alloc(512u));

  float *BS0=SMALLF+0, *BS1=SMALLF+128, *BS2=SMALLF+256;
  float *BG0=SMALLF+384;
  float *W0=SMALLF+6576, *B0=SMALLF+31152;
  float *W1=SMALLF+31160, *B1=SMALLF+31288;
  float *W2=SMALLF+31304, *B2=SMALLF+31320;

  k_sniff<<<1, 256, 0, stream>>>((const unsigned*)x_main, FLAG);
  k_zero<<<1, 256, 0, stream>>>((float*)ZPAD, 128);
  k_cvt_small<<<123, 256, 0, stream>>>(d_in[4], d_in[10], d_in[16], d_in[6], d_in[8],
      d_in[12], d_in[14], d_in[18], d_in[20], d_in[21], d_in[22], d_in[23], d_in[24],
      d_in[25], d_in[26], SMALLF, FLAG);
  k_bcol<<<1, 256, 0, stream>>>(SMALLF, BCOL);
  k_mzero<<<36, 256, 0, stream>>>(MB);
  k_mbeta<<<dim3(9,24), 256, 0, stream>>>(d_in[7], FLAG, W0, MB);
  k_wsm<<<36, 256, 0, stream>>>(MB, WSMALL);

  k_permW<128><<<dim3((3538944+255)/256),256, 0, stream>>>(d_in[5],  WG0,            3538944, FLAG);
  k_permW<128><<<dim3((9216+255)/256),   256, 0, stream>>>(d_in[11], WSMALL,           9216, FLAG);
  k_permW<128><<<dim3((9216+255)/256),   256, 0, stream>>>(d_in[13], WSMALL + 8*1152,  9216, FLAG);
  k_permW<128><<<dim3((18432+255)/256),  256, 0, stream>>>(d_in[17], WSMALL + 16*1152, 18432, FLAG);
  k_permW<128><<<dim3((18432+255)/256),  256, 0, stream>>>(d_in[19], WSMALL + 32*1152, 18432, FLAG);

  k_ln_partial<<<dim3(128,2), 256, 0, stream>>>(x_main, FLAG, LNP);
  k_ln_final<<<2, 128, 0, stream>>>(LNP, STATS);
  k_seg_means<<<dim3(64,2), 256, 0, stream>>>(f_sem, FLAG, segmap, MEANS);
  k_tt<<<dim3(216,2), 256, 0, stream>>>(d_in[3], d_in[9], d_in[15], FLAG, MEANS, WTT);
  k_A<<<PTOT, 192, 0, stream>>>(segmap, AHL);

  // G1: h = relu(conv3x3(sem, ws_l)) for all 3 layers -> HS (4608,384)
  // via folded weights: K = 9 dyx * (64 A_hi + 64 A_lo) = 1152 (was 6912)
  k_gemm<true, bf16><<<dim3(72,6), 256, 0, stream>>>(AHL, 128, 0, 128, WTT, 1152, (size_t)384*1152,
      BS0, BS1, BS2, 128, HS, 384, 0, 384, ZPAD);
  // small GEMMs (per-layer A columns)
  k_gemm<false, float><<<dim3(72,1), 256, 0, stream>>>(HS, 384, 128, 128, WSMALL, 1152, 0,
      BCOL, BCOL, BCOL, 9999, GBS, 16, 0, 64, ZPAD);
  k_gemm<false, float><<<dim3(72,1), 256, 0, stream>>>(HS, 384, 256, 128, WSMALL + 16*1152, 1152, 0,
      BCOL+16, BCOL+16, BCOL+16, 9999, GBS+16, 32, 0, 64, ZPAD);
  k_gemm<false, float><<<dim3(72,1), 256, 0, stream>>>(HS, 384, 0, 128, WSMALL + 48*1152, 1152, 0,
      BCOL+48, BCOL+48, BCOL+48, 9999, GBS+48, 16, 0, 64, ZPAD);

  // layer-0: z0 = bias0 + z0beta + sum_c xn*(1+gamma)*w0   (gamma fused, never materialized)
  k_z0init<<<144, 256, 0, stream>>>(B0, GBS, Z0);
  k_gfuse<<<dim3(36,24), 256, 0, stream>>>(HS, WG0, BG0, x_main, FLAG, STATS, W0, Z0, ZPAD);
  k_sp<<<144, 256, 0, stream>>>(Z0, 36864);

  k_ln_small<<<2, 256, 0, stream>>>(Z0, 18432, STATS + 4);
  k_F1<<<18, 256, 0, stream>>>(Z0, GBS, STATS + 4, W1, B1, Z1);
  k_ln_small<<<2, 256, 0, stream>>>(Z1, 36864, STATS + 8);
  k_F2<<<18, 256, 0, stream>>>(Z1, GBS, STATS + 8, W2, B2, d_out, FLAG);
}

// Round 5
// 621.653 us; speedup vs baseline: 1.1133x; 1.0206x over previous
//
#include <hip/hip_runtime.h>
#include <hip/hip_bf16.h>

typedef __hip_bfloat16 bf16;
typedef __bf16 v8bf __attribute__((ext_vector_type(8)));
typedef float v4f __attribute__((ext_vector_type(4)));

#define PB 2304
#define PTOT 4608

__device__ __forceinline__ float b2f(bf16 x){ return __bfloat162float(x); }
__device__ __forceinline__ bf16 f2b(float x){ return __float2bfloat16(x); }
__device__ __forceinline__ float softplus_f(float x){
  return fmaxf(x, 0.f) + log1pf(expf(-fabsf(x)));
}
__device__ __forceinline__ float LD(const void* src, size_t i, int fl){
  return fl ? ((const float*)src)[i] : b2f(((const bf16*)src)[i]);
}

// async global->LDS DMA, 16B per lane; LDS dest is wave-uniform base + lane*16
__device__ __forceinline__ void gload_lds16(const void* g, void* l){
  __builtin_amdgcn_global_load_lds(
      (const __attribute__((address_space(1))) void*)g,
      (__attribute__((address_space(3))) void*)l, 16, 0, 0);
}

// ---------- dtype sniffer (flag=1 if f32) + ZPAD zeroing ----------
__global__ __launch_bounds__(256) void k_sniff(const unsigned* __restrict__ x, int* __restrict__ flag,
                                               float* __restrict__ zp){
  int t = threadIdx.x;
  if (t < 128) zp[t] = 0.f;
  int cnt = 0;
  for (int i = t; i < 4096; i += 256){
    unsigned e = (x[i] >> 8) & 0x7F;
    if (e >= 0x38 && e <= 0x42) cnt++;
  }
  for (int off = 32; off; off >>= 1) cnt += __shfl_down(cnt, off, 64);
  __shared__ int sc[4];
  if ((t & 63) == 0) sc[t >> 6] = cnt;
  __syncthreads();
  if (t == 0) *flag = (sc[0]+sc[1]+sc[2]+sc[3] < 2048) ? 1 : 0;
}

// ---------- merged small-tensor canonicalization to f32 + MB zeroing ----------
__global__ __launch_bounds__(256) void k_cvt_small(
    const void* s4, const void* s10, const void* s16, const void* s6, const void* s8,
    const void* s12, const void* s14, const void* s18, const void* s20,
    const void* s21, const void* s22, const void* s23, const void* s24,
    const void* s25, const void* s26,
    float* __restrict__ dst, const int* __restrict__ flag, float* __restrict__ MB){
  int i = blockIdx.x*256 + threadIdx.x;
  if (i >= 40537) return;
  if (i >= 31321){ MB[i - 31321] = 0.f; return; }
  int fl = *flag;
  const void* src; size_t off;
  if      (i < 128)   { src = s4;  off = i; }
  else if (i < 256)   { src = s10; off = i - 128; }
  else if (i < 384)   { src = s16; off = i - 256; }
  else if (i < 3456)  { src = s6;  off = i - 384; }
  else if (i < 6528)  { src = s8;  off = i - 3456; }
  else if (i < 6536)  { src = s12; off = i - 6528; }
  else if (i < 6544)  { src = s14; off = i - 6536; }
  else if (i < 6560)  { src = s18; off = i - 6544; }
  else if (i < 6576)  { src = s20; off = i - 6560; }
  else if (i < 31152) { src = s21; off = i - 6576; }
  else if (i < 31160) { src = s22; off = i - 31152; }
  else if (i < 31288) { src = s23; off = i - 31160; }
  else if (i < 31304) { src = s24; off = i - 31288; }
  else if (i < 31320) { src = s25; off = i - 31304; }
  else                { src = s26; off = i - 31320; }
  dst[i] = LD(src, off, fl);
}

// ---------- BCOL[64]: per-column biases for the small GEMMs ----------
__global__ __launch_bounds__(256) void k_bcol(const float* __restrict__ SMALLF, float* __restrict__ BCOL){
  int t = threadIdx.x;
  const float* BG1 = SMALLF + 6528; const float* BB1 = SMALLF + 6536;
  const float* BG2 = SMALLF + 6544; const float* BB2 = SMALLF + 6560;
  const float* BB0 = SMALLF + 3456; const float* W0  = SMALLF + 6576;
  if (t < 8)       BCOL[t] = BG1[t];
  else if (t < 16) BCOL[t] = BB1[t-8];
  else if (t < 32) BCOL[t] = BG2[t-16];
  else if (t < 48) BCOL[t] = BB2[t-32];
  else if (t < 64) BCOL[t] = 0.f;
  float part[8] = {0,0,0,0,0,0,0,0};
  for (int c = t; c < 3072; c += 256){
    float bb = BB0[c];
    #pragma unroll
    for (int oc = 0; oc < 8; oc++) part[oc] += bb*W0[oc*3072 + c];
  }
  __shared__ float red[4][8];
  int wv = t >> 6, lane = t & 63;
  #pragma unroll
  for (int oc = 0; oc < 8; oc++){
    float v = part[oc];
    for (int off = 32; off; off >>= 1) v += __shfl_down(v, off, 64);
    if (lane == 0) red[wv][oc] = v;
  }
  __syncthreads();
  if (t < 8) BCOL[48 + t] = red[0][t] + red[1][t] + red[2][t] + red[3][t];
}

// ---------- M_beta[oc][j=dyx*128+ic] = sum_n wb0[n, ic, dyx] * w0[oc, n] ----------
__global__ __launch_bounds__(256) void k_mbeta(const void* __restrict__ wb0, const int* __restrict__ flag,
                                               const float* __restrict__ w0f, float* __restrict__ MB){
  int jb = blockIdx.x, nb = blockIdx.y, t = threadIdx.x;
  int fl = *flag;
  int jl = t & 127, nh = t >> 7;
  int j = jb*128 + jl;
  int src = jl*9 + jb;
  float acc[8] = {0,0,0,0,0,0,0,0};
  int n0 = nb*128 + nh*64;
  for (int i = 0; i < 64; i++){
    int n = n0 + i;
    float wv = LD(wb0, (size_t)n*1152 + src, fl);
    #pragma unroll
    for (int oc = 0; oc < 8; oc++) acc[oc] += wv*w0f[oc*3072 + n];
  }
  #pragma unroll
  for (int oc = 0; oc < 8; oc++) atomicAdd(&MB[oc*1152 + j], acc[oc]);
}

__global__ __launch_bounds__(256) void k_wsm(const float* __restrict__ MB, bf16* __restrict__ WSMALL){
  int i = blockIdx.x*256 + threadIdx.x;
  if (i >= 9216) return;
  float v = MB[i];
  bf16 hi = f2b(v);
  WSMALL[48*1152 + i] = hi;
  WSMALL[56*1152 + i] = f2b(v - b2f(hi));
}

// ---------- weight permute (oc, ic, 3,3) -> (oc, dyx, ic), bf16 out ----------
template<int ICW>
__global__ __launch_bounds__(256) void k_permW(const void* __restrict__ src, bf16* __restrict__ dst,
                                               int total, const int* __restrict__ flag){
  int idx = blockIdx.x*256 + threadIdx.x;
  if (idx >= total) return;
  int oc = idx / (9*ICW);
  int rr = idx % (9*ICW);
  int dyx = rr / ICW, ic = rr % ICW;
  size_t si = (size_t)(oc*ICW + ic)*9 + dyx;
  dst[idx] = f2b(LD(src, si, *flag));
}

// ---------- segment means over 24x24 downsampled segmap ----------
__global__ __launch_bounds__(256) void k_seg_means(const void* __restrict__ f_sem, const int* __restrict__ flag,
                                                   const int* __restrict__ segmap,
                                                   float* __restrict__ means){
  int s = blockIdx.x, b = blockIdx.y, t = threadIdx.x;
  int fl = *flag;
  __shared__ int sid[576];
  for (int i = t; i < 576; i += 256){
    int y = i / 24, x = i % 24;
    int v = segmap[b*336*336 + (y*14)*336 + x*14];
    sid[i] = min(max(v, 0), 63);
  }
  __syncthreads();
  float a0=0.f, a1=0.f, a2=0.f; int cnt = 0;
  for (int i = 0; i < 576; i++){
    if (sid[i] == s){
      cnt++;
      a0 += LD(f_sem, (size_t)(b*768 + t      )*576 + i, fl);
      a1 += LD(f_sem, (size_t)(b*768 + t + 256)*576 + i, fl);
      a2 += LD(f_sem, (size_t)(b*768 + t + 512)*576 + i, fl);
    }
  }
  float inv = cnt > 0 ? 1.f/(float)cnt : 0.f;
  float* o = means + (size_t)(b*64 + s)*768;
  o[t] = a0*inv; o[t+256] = a1*inv; o[t+512] = a2*inv;
}

// ---------- TT[b][oc][dyx][s] = sum_ic ws_l[oc][ic][dyx] * means[b][s][ic] ----------
__global__ __launch_bounds__(256) void k_tt(const void* __restrict__ ws0, const void* __restrict__ ws1,
    const void* __restrict__ ws2, const int* __restrict__ flag,
    const float* __restrict__ means, bf16* __restrict__ WTT){
  int bx = blockIdx.x;
  int dyx = bx / 24, ocb = bx % 24;
  int b = blockIdx.y, t = threadIdx.x;
  int fl = *flag;
  int ocg0 = ocb*16;
  const void* wsrc; int ocl0 = ocg0;
  if (ocl0 < 128) wsrc = ws0;
  else if (ocl0 < 256){ wsrc = ws1; ocl0 -= 128; }
  else { wsrc = ws2; ocl0 -= 256; }
  __shared__ float wl[16][768];
  for (int ol = 0; ol < 16; ol++)
    for (int ic = t; ic < 768; ic += 256)
      wl[ol][ic] = LD(wsrc, (size_t)(ocl0 + ol)*6912 + (size_t)ic*9 + dyx, fl);
  __syncthreads();
  int s = t & 63, og = t >> 6;
  const float* mr = means + ((size_t)b*64 + s)*768;
  float acc[4] = {0.f, 0.f, 0.f, 0.f};
  for (int ic = 0; ic < 768; ic += 4){
    float4 m = *reinterpret_cast<const float4*>(mr + ic);
    #pragma unroll
    for (int k = 0; k < 4; k++){
      const float* w = &wl[og + k*4][ic];
      acc[k] += m.x*w[0] + m.y*w[1] + m.z*w[2] + m.w*w[3];
    }
  }
  #pragma unroll
  for (int k = 0; k < 4; k++){
    bf16 h = f2b(acc[k]);
    size_t base = ((size_t)(b*384 + ocg0 + og + k*4))*1152 + (size_t)dyx*128 + s;
    WTT[base] = h;
    WTT[base + 64] = h;
  }
}

// ---------- per-pixel segment weights (antialiased bilinear 336->48), bf16 hi/lo out ----------
__global__ __launch_bounds__(192) void k_A(const int* __restrict__ segmap, bf16* __restrict__ AHL){
  int blk = blockIdx.x;
  int b = blk / PB, rem = blk % PB, yo = rem / 48, xo = rem % 48;
  __shared__ float accs[64];
  int t = threadIdx.x;
  if (t < 64) accs[t] = 0.f;
  __syncthreads();
  if (t < 169){
    int ty = t / 13, tx = t % 13;
    int jy = 7*yo - 3 + ty, jx = 7*xo - 3 + tx;
    if (jy >= 0 && jy < 336 && jx >= 0 && jx < 336){
      int wy = 7 - abs(ty - 6), wx = 7 - abs(tx - 6);
      int sv = segmap[b*336*336 + jy*336 + jx];
      sv = min(max(sv, 0), 63);
      atomicAdd(&accs[sv], (float)(wy*wx));
    }
  }
  int sumy = 0, sumx = 0;
  for (int k = 0; k < 13; k++){
    int jy = 7*yo - 3 + k; if (jy >= 0 && jy < 336) sumy += 7 - abs(k - 6);
    int jx = 7*xo - 3 + k; if (jx >= 0 && jx < 336) sumx += 7 - abs(k - 6);
  }
  __syncthreads();
  if (t < 64){
    float v = accs[t] / (float)(sumy*sumx);
    bf16 hi = f2b(v);
    AHL[(size_t)blk*128 + t] = hi;
    AHL[(size_t)blk*128 + 64 + t] = f2b(v - b2f(hi));
  }
}

// ---------- LN stats over x_main ----------
__global__ __launch_bounds__(256) void k_ln_partial(const void* __restrict__ x, const int* __restrict__ flag,
                                                    float2* __restrict__ part){
  int b = blockIdx.y, blk = blockIdx.x, t = threadIdx.x;
  int fl = *flag;
  size_t base = (size_t)b*7077888 + (size_t)blk*55296;
  float s = 0.f, sq = 0.f;
  for (int i = 0; i < 216; i++){
    float v = LD(x, base + t + i*256, fl);
    s += v; sq += v*v;
  }
  for (int off = 32; off; off >>= 1){ s += __shfl_down(s, off, 64); sq += __shfl_down(sq, off, 64); }
  __shared__ float ls[4], lq[4];
  int w = t >> 6, lane = t & 63;
  if (lane == 0){ ls[w] = s; lq[w] = sq; }
  __syncthreads();
  if (t == 0) part[b*128 + blk] = make_float2(ls[0]+ls[1]+ls[2]+ls[3], lq[0]+lq[1]+lq[2]+lq[3]);
}

__global__ void k_ln_final(const float2* __restrict__ part, float* __restrict__ stats){
  int b = blockIdx.x, t = threadIdx.x;
  float2 v = part[b*128 + t];
  float s = v.x, sq = v.y;
  for (int off = 32; off; off >>= 1){ s += __shfl_down(s, off, 64); sq += __shfl_down(sq, off, 64); }
  __shared__ float ls[2], lq[2];
  if ((t & 63) == 0){ ls[t>>6] = s; lq[t>>6] = sq; }
  __syncthreads();
  if (t == 0){
    s = ls[0]+ls[1]; sq = lq[0]+lq[1];
    const float N = 7077888.f;
    float mean = s/N; float var = sq/N - mean*mean; var = fmaxf(var, 0.f);
    stats[b*2] = mean; stats[b*2+1] = rsqrtf(var + 1e-12f);
  }
}

// ---------- softplus-in-place + LN stats (fused) ----------
__global__ __launch_bounds__(256) void k_spln(float* __restrict__ z, int cnt, float* __restrict__ stats){
  int b = blockIdx.x, t = threadIdx.x;
  float* p = z + (size_t)b*cnt;
  float s = 0.f, sq = 0.f;
  for (int i = t; i < cnt; i += 256){
    float v = softplus_f(p[i]);
    p[i] = v;
    s += v; sq += v*v;
  }
  for (int off = 32; off; off >>= 1){ s += __shfl_down(s, off, 64); sq += __shfl_down(sq, off, 64); }
  __shared__ float ls[4], lq[4];
  int w = t >> 6, lane = t & 63;
  if (lane == 0){ ls[w] = s; lq[w] = sq; }
  __syncthreads();
  if (t == 0){
    s = ls[0]+ls[1]+ls[2]+ls[3]; sq = lq[0]+lq[1]+lq[2]+lq[3];
    float mean = s/(float)cnt; float var = sq/(float)cnt - mean*mean; var = fmaxf(var, 0.f);
    stats[b*2] = mean; stats[b*2+1] = rsqrtf(var + 1e-12f);
  }
}

__global__ __launch_bounds__(256) void k_ln_small(const float* __restrict__ z, int cnt, float* __restrict__ stats){
  int b = blockIdx.x, t = threadIdx.x;
  const float* p = z + (size_t)b*cnt;
  float s = 0.f, sq = 0.f;
  for (int i = t; i < cnt; i += 256){ float v = p[i]; s += v; sq += v*v; }
  for (int off = 32; off; off >>= 1){ s += __shfl_down(s, off, 64); sq += __shfl_down(sq, off, 64); }
  __shared__ float ls[4], lq[4];
  int w = t >> 6, lane = t & 63;
  if (lane == 0){ ls[w] = s; lq[w] = sq; }
  __syncthreads();
  if (t == 0){
    s = ls[0]+ls[1]+ls[2]+ls[3]; sq = lq[0]+lq[1]+lq[2]+lq[3];
    float mean = s/(float)cnt; float var = sq/(float)cnt - mean*mean; var = fmaxf(var, 0.f);
    stats[b*2] = mean; stats[b*2+1] = rsqrtf(var + 1e-12f);
  }
}

// ---------- shared MFMA GEMM body (BK=64, 64x64 tile, round-2 2-barrier structure) ----------
template<bool RELU, typename OT>
__device__ __forceinline__ void gemm_body(
    const bf16* __restrict__ Asrc, int AS, int acol, int ICW,
    const bf16* __restrict__ W, int K, size_t wbstride,
    const float* __restrict__ bp0, const float* __restrict__ bp1, const float* __restrict__ bp2, int seg,
    OT* __restrict__ out, int N, int ncb, int ldo, const bf16* __restrict__ zpad,
    int m0, int n0, bf16 (*Al)[64], bf16 (*Bl)[64])
{
  int t = threadIdx.x;
  int wv = t >> 6, lane = t & 63;
  int lr8 = lane >> 3, sseg = (lane & 7) ^ lr8;   // source 16B-seg (swizzled)
  int b = m0 >= PB ? 1 : 0;

  int ya[2], xa[2]; bool bv[2]; const bf16* wb[2];
  #pragma unroll
  for (int i = 0; i < 2; i++){
    int sp = (m0 - b*PB) + wv*16 + i*8 + lr8;
    ya[i] = sp / 48; xa[i] = sp % 48;
    int nrow = ncb + n0 + wv*16 + i*8 + lr8;
    bv[i] = nrow < N;
    wb[i] = W + (size_t)b*wbstride + (size_t)nrow*K + sseg*8;
  }

  int wm = (wv >> 1)*32, wn = (wv & 1)*32;
  int lrow = lane & 15, quad = lane >> 4;
  int sx = lrow & 7;
  int o0 = ((quad    ) ^ sx)*8;
  int o1 = ((quad + 4) ^ sx)*8;

  v4f acc00 = {0,0,0,0}, acc01 = {0,0,0,0}, acc10 = {0,0,0,0}, acc11 = {0,0,0,0};

  int dyx = 0, ic0 = 0;
  int ktn = K / 64;
  for (int kt = 0; kt < ktn; kt++){
    int dy = dyx/3 - 1, dx = dyx%3 - 1;
    #pragma unroll
    for (int i = 0; i < 2; i++){
      int ys = ya[i] + dy, xs = xa[i] + dx;
      const bf16* ga = (ys >= 0 && ys < 48 && xs >= 0 && xs < 48)
        ? Asrc + (size_t)(b*PB + ys*48 + xs)*AS + acol + ic0 + sseg*8 : zpad;
      gload_lds16(ga, &Al[wv*16 + i*8][0]);
      const bf16* gb = bv[i] ? wb[i] + kt*64 : zpad;
      gload_lds16(gb, &Bl[wv*16 + i*8][0]);
    }
    asm volatile("s_waitcnt vmcnt(0)" ::: "memory");
    __syncthreads();
    v8bf a00 = *reinterpret_cast<const v8bf*>(&Al[wm      + lrow][o0]);
    v8bf a10 = *reinterpret_cast<const v8bf*>(&Al[wm + 16 + lrow][o0]);
    v8bf a01 = *reinterpret_cast<const v8bf*>(&Al[wm      + lrow][o1]);
    v8bf a11 = *reinterpret_cast<const v8bf*>(&Al[wm + 16 + lrow][o1]);
    v8bf b00 = *reinterpret_cast<const v8bf*>(&Bl[wn      + lrow][o0]);
    v8bf b10 = *reinterpret_cast<const v8bf*>(&Bl[wn + 16 + lrow][o0]);
    v8bf b01 = *reinterpret_cast<const v8bf*>(&Bl[wn      + lrow][o1]);
    v8bf b11 = *reinterpret_cast<const v8bf*>(&Bl[wn + 16 + lrow][o1]);
    acc00 = __builtin_amdgcn_mfma_f32_16x16x32_bf16(a00, b00, acc00, 0, 0, 0);
    acc00 = __builtin_amdgcn_mfma_f32_16x16x32_bf16(a01, b01, acc00, 0, 0, 0);
    acc01 = __builtin_amdgcn_mfma_f32_16x16x32_bf16(a00, b10, acc01, 0, 0, 0);
    acc01 = __builtin_amdgcn_mfma_f32_16x16x32_bf16(a01, b11, acc01, 0, 0, 0);
    acc10 = __builtin_amdgcn_mfma_f32_16x16x32_bf16(a10, b00, acc10, 0, 0, 0);
    acc10 = __builtin_amdgcn_mfma_f32_16x16x32_bf16(a11, b01, acc10, 0, 0, 0);
    acc11 = __builtin_amdgcn_mfma_f32_16x16x32_bf16(a10, b10, acc11, 0, 0, 0);
    acc11 = __builtin_amdgcn_mfma_f32_16x16x32_bf16(a11, b11, acc11, 0, 0, 0);
    __syncthreads();
    ic0 += 64; if (ic0 == ICW){ ic0 = 0; dyx++; }
  }

  auto store_tile = [&](v4f a, int mi, int ni){
    int gcol = ncb + n0 + wn + ni*16 + lrow;
    if (gcol >= N) return;
    int sel = gcol / seg; sel = sel > 2 ? 2 : sel;
    const float* bp = sel == 0 ? bp0 : (sel == 1 ? bp1 : bp2);
    float bias = bp[gcol - sel*seg];
    int rowb = m0 + wm + mi*16 + quad*4;
    #pragma unroll
    for (int rg = 0; rg < 4; rg++){
      float v = a[rg] + bias;
      if (RELU) v = fmaxf(v, 0.f);
      if constexpr (sizeof(OT) == 2) out[(size_t)(rowb+rg)*ldo + (gcol - ncb)] = f2b(v);
      else                           out[(size_t)(rowb+rg)*ldo + (gcol - ncb)] = (OT)v;
    }
  };
  store_tile(acc00, 0, 0); store_tile(acc01, 0, 1);
  store_tile(acc10, 1, 0); store_tile(acc11, 1, 1);
}

template<bool RELU, typename OT>
__global__ __launch_bounds__(256) void k_gemm(
    const bf16* __restrict__ Asrc, int AS, int acol, int ICW,
    const bf16* __restrict__ W, int K, size_t wbstride,
    const float* __restrict__ bp0, const float* __restrict__ bp1, const float* __restrict__ bp2, int seg,
    OT* __restrict__ out, int N, int ncb, int ldo, const bf16* __restrict__ zpad)
{
  __shared__ __align__(16) bf16 Al[64][64];
  __shared__ __align__(16) bf16 Bl[64][64];
  gemm_body<RELU, OT>(Asrc, AS, acol, ICW, W, K, wbstride, bp0, bp1, bp2, seg,
                      out, N, ncb, ldo, zpad, blockIdx.x*64, blockIdx.y*64, Al, Bl);
}

// merged 3 small GEMMs: blockIdx.y selects {gamma1, beta1+gamma2, beta2+z0beta} config
__global__ __launch_bounds__(256) void k_gsmall(
    const bf16* __restrict__ HS, const bf16* __restrict__ WSMALL, const float* __restrict__ BCOL,
    float* __restrict__ GBS, const bf16* __restrict__ zpad)
{
  __shared__ __align__(16) bf16 Al[64][64];
  __shared__ __align__(16) bf16 Bl[64][64];
  int y = blockIdx.y;
  int acol = y == 0 ? 128 : (y == 1 ? 256 : 0);
  const bf16* W = WSMALL + (y == 0 ? 0 : (y == 1 ? 16*1152 : 48*1152));
  const float* bp = BCOL + (y == 0 ? 0 : (y == 1 ? 16 : 48));
  float* out = GBS + (y == 0 ? 0 : (y == 1 ? 16 : 48));
  int N = y == 1 ? 32 : 16;
  gemm_body<false, float>(HS, 384, acol, 128, W, 1152, 0, bp, bp, bp, 9999,
                          out, N, 0, 64, zpad, blockIdx.x*64, 0, Al, Bl);
}

// ---------- fused gamma GEMM + z0 contraction ----------
// N-tile 64 (acc[2][4]=32 AGPR) + __launch_bounds__(256,4): target 4 blocks/CU
// (round-4 diagnosis: VGPR 140 + 64 AGPR -> 2 waves/SIMD -> latency-bound at Occ 9.5%).
// grid (36, 48), block 256. tile 128p x 64c, BK=64, wave = 32p x 64c.
__global__ __launch_bounds__(256, 4) void k_gfuse(
    const bf16* __restrict__ HS, const bf16* __restrict__ WG0, const float* __restrict__ BG0,
    const void* __restrict__ x, const int* __restrict__ flag, const float* __restrict__ stats,
    const float* __restrict__ w0f, float* __restrict__ z0, const bf16* __restrict__ zpad)
{
  __shared__ __align__(16) char lds_raw[36096];
  bf16 (*Al)[64]  = (bf16(*)[64])lds_raw;                  // [128][64] (DMA dest)
  bf16 (*Bl)[64]  = (bf16(*)[64])(lds_raw + 16384);        // [64][64]  (DMA dest)
  float (*xl)[132] = (float(*)[132])lds_raw;               // [64][132] epilogue reuse (33792 B)
  float (*w0l)[64] = (float(*)[64])(lds_raw + 33792);      // [8][64]
  float* bg0l = (float*)(lds_raw + 35840);                 // [64]

  int t = threadIdx.x;
  int m0 = blockIdx.x*128, n0 = blockIdx.y*64;
  int b = m0 >= PB ? 1 : 0;
  int fl = *flag;

  int wv = t >> 6, lane = t & 63;
  int lr8 = lane >> 3, sseg = (lane & 7) ^ lr8;   // swizzled source seg
  int spbase = m0 - b*PB;

  int ya[4], xa[4];
  #pragma unroll
  for (int i = 0; i < 4; i++){
    int sp = spbase + wv*32 + i*8 + lr8;
    ya[i] = sp / 48; xa[i] = sp % 48;
  }
  const bf16* wgb = WG0 + (size_t)(n0 + wv*16 + lr8)*1152 + sseg*8;

  int wm = wv*32, lrow = lane & 15, quad = lane >> 4;
  int sx = lrow & 7;

  v4f acc[2][4];
  #pragma unroll
  for (int mi = 0; mi < 2; mi++)
    #pragma unroll
    for (int ni = 0; ni < 4; ni++) acc[mi][ni] = (v4f){0,0,0,0};

  for (int kt = 0; kt < 18; kt++){
    int dyx = kt >> 1, icr = (kt & 1) << 6;
    int dy = dyx/3 - 1, dx = dyx%3 - 1;
    #pragma unroll
    for (int i = 0; i < 4; i++){
      int ys = ya[i] + dy, xs = xa[i] + dx;
      const bf16* ga = (ys >= 0 && ys < 48 && xs >= 0 && xs < 48)
        ? HS + (size_t)(b*PB + ys*48 + xs)*384 + icr + sseg*8 : zpad;
      gload_lds16(ga, &Al[wv*32 + i*8][0]);
    }
    #pragma unroll
    for (int i = 0; i < 2; i++)
      gload_lds16(wgb + (size_t)(i*8)*1152 + dyx*128 + icr, &Bl[wv*16 + i*8][0]);
    asm volatile("s_waitcnt vmcnt(0)" ::: "memory");
    __syncthreads();
    #pragma unroll
    for (int kh = 0; kh < 2; kh++){
      int oa = ((kh*4 + quad) ^ sx)*8;
      v8bf a0 = *reinterpret_cast<const v8bf*>(&Al[wm      + lrow][oa]);
      v8bf a1 = *reinterpret_cast<const v8bf*>(&Al[wm + 16 + lrow][oa]);
      #pragma unroll
      for (int ni = 0; ni < 4; ni++){
        v8bf bn = *reinterpret_cast<const v8bf*>(&Bl[ni*16 + lrow][oa]);
        acc[0][ni] = __builtin_amdgcn_mfma_f32_16x16x32_bf16(a0, bn, acc[0][ni], 0, 0, 0);
        acc[1][ni] = __builtin_amdgcn_mfma_f32_16x16x32_bf16(a1, bn, acc[1][ni], 0, 0, 0);
      }
    }
    __syncthreads();
  }

  // ---- epilogue: stage w0 slice + bg0 slice + x tile (64 ch x 128 px) ----
  for (int i = t; i < 512; i += 256) w0l[i >> 6][i & 63] = w0f[(size_t)(i >> 6)*3072 + n0 + (i & 63)];
  if (t < 64) bg0l[t] = BG0[n0 + t];

  if (fl){
    const float* xp = (const float*)x + ((size_t)(b*3072 + n0))*2304 + spbase;
    #pragma unroll
    for (int it = 0; it < 8; it++){
      int idx = it*256 + t;
      int row = idx >> 5, c4 = (idx & 31)*4;
      float4 v = *reinterpret_cast<const float4*>(xp + (size_t)row*2304 + c4);
      *reinterpret_cast<float4*>(&xl[row][c4]) = v;
    }
  } else {
    const bf16* xp = (const bf16*)x + ((size_t)(b*3072 + n0))*2304 + spbase;
    #pragma unroll
    for (int it = 0; it < 4; it++){
      int idx = it*256 + t;
      int row = idx >> 4, c8 = (idx & 15)*8;
      v8bf v = *reinterpret_cast<const v8bf*>(xp + (size_t)row*2304 + c8);
      float4 f0, f1;
      f0.x = (float)v[0]; f0.y = (float)v[1]; f0.z = (float)v[2]; f0.w = (float)v[3];
      f1.x = (float)v[4]; f1.y = (float)v[5]; f1.z = (float)v[6]; f1.w = (float)v[7];
      *reinterpret_cast<float4*>(&xl[row][c8])     = f0;
      *reinterpret_cast<float4*>(&xl[row][c8 + 4]) = f1;
    }
  }
  __syncthreads();

  float mean = stats[b*2], rstd = stats[b*2+1];

  // oc split in 2 groups of 4 to cap register pressure (s[2][4][4] = 32 VGPR)
  for (int og2 = 0; og2 < 2; og2++){
    float s[2][4][4];
    #pragma unroll
    for (int mi = 0; mi < 2; mi++)
      #pragma unroll
      for (int rg = 0; rg < 4; rg++)
        #pragma unroll
        for (int oc = 0; oc < 4; oc++) s[mi][rg][oc] = 0.f;
    #pragma unroll
    for (int mi = 0; mi < 2; mi++){
      int pl = wm + mi*16 + quad*4;
      #pragma unroll
      for (int nis = 0; nis < 4; nis++){
        int c = nis*16 + lrow;
        float bg = bg0l[c];
        float w0v[4];
        #pragma unroll
        for (int oc = 0; oc < 4; oc++) w0v[oc] = w0l[og2*4 + oc][c];
        #pragma unroll
        for (int rg = 0; rg < 4; rg++){
          float gv = acc[mi][nis][rg] + bg;
          float xn = (xl[c][pl + rg] - mean)*rstd;
          float tv = xn*(1.f + gv);
          #pragma unroll
          for (int oc = 0; oc < 4; oc++) s[mi][rg][oc] += tv*w0v[oc];
        }
      }
    }
    #pragma unroll
    for (int mi = 0; mi < 2; mi++){
      #pragma unroll
      for (int rg = 0; rg < 4; rg++)
        #pragma unroll
        for (int oc = 0; oc < 4; oc++){
          float v = s[mi][rg][oc];
          v += __shfl_xor(v, 1, 64);
          v += __shfl_xor(v, 2, 64);
          v += __shfl_xor(v, 4, 64);
          v += __shfl_xor(v, 8, 64);
          s[mi][rg][oc] = v;
        }
      if (lrow == 0){
        int p = m0 + wm + mi*16 + quad*4;
        #pragma unroll
        for (int rg = 0; rg < 4; rg++)
          #pragma unroll
          for (int oc = 0; oc < 4; oc++)
            atomicAdd(&z0[(size_t)(p + rg)*8 + og2*4 + oc], s[mi][rg][oc]);
      }
    }
  }
}

// ---------- z0 init: bias0 + beta-contraction (GBS cols 48..55 hi + 56..63 lo) ----------
__global__ __launch_bounds__(256) void k_z0init(const float* __restrict__ b0f, const float* __restrict__ GBS,
                                                float* __restrict__ z0){
  int i = blockIdx.x*256 + threadIdx.x;
  if (i >= 36864) return;
  int p = i >> 3, oc = i & 7;
  z0[i] = b0f[oc] + GBS[(size_t)p*64 + 48 + oc] + GBS[(size_t)p*64 + 56 + oc];
}

__global__ __launch_bounds__(256) void k_F1(const float* __restrict__ z0, const float* __restrict__ GBS,
    const float* __restrict__ stats, const float* __restrict__ w1f, const float* __restrict__ b1f,
    float* __restrict__ z1){
  int p = blockIdx.x*256 + threadIdx.x;
  if (p >= PTOT) return;
  int b = p / PB;
  float mean = stats[b*2], rstd = stats[b*2+1];
  const float* zr = z0 + (size_t)p*8;
  const float* gr = GBS + (size_t)p*64;
  float yv[8];
  #pragma unroll
  for (int c = 0; c < 8; c++) yv[c] = (zr[c] - mean)*rstd*(1.f + gr[c]) + gr[8 + c];
  #pragma unroll
  for (int oc = 0; oc < 16; oc++){
    float s = b1f[oc];
    #pragma unroll
    for (int c = 0; c < 8; c++) s += yv[c]*w1f[oc*8 + c];
    z1[(size_t)p*16 + oc] = softplus_f(s);
  }
}

__global__ __launch_bounds__(256) void k_F2(const float* __restrict__ z1, const float* __restrict__ GBS,
    const float* __restrict__ stats, const float* __restrict__ w2f, const float* __restrict__ b2f,
    void* __restrict__ outp, const int* __restrict__ flag){
  int p = blockIdx.x*256 + threadIdx.x;
  if (p >= PTOT) return;
  int b = p / PB;
  float mean = stats[b*2], rstd = stats[b*2+1];
  const float* zr = z1 + (size_t)p*16;
  const float* gr = GBS + (size_t)p*64 + 16;
  float s = b2f[0];
  #pragma unroll
  for (int c = 0; c < 16; c++){
    float yv = (zr[c] - mean)*rstd*(1.f + gr[c]) + gr[16 + c];
    s += yv*w2f[c];
  }
  float r = softplus_f(s);
  if (*flag) ((float*)outp)[p] = r;
  else       ((bf16*)outp)[p] = f2b(r);
}

extern "C" void kernel_launch(void* const* d_in, const int* in_sizes, int n_in,
                              void* d_out, int out_size, void* d_ws, size_t ws_size,
                              hipStream_t stream){
  const void* x_main = d_in[0];
  const void* f_sem  = d_in[1];
  const int*  segmap = (const int*)d_in[2];

  char* ws = (char*)d_ws;
  size_t o = 0;
  auto alloc = [&](size_t bytes){ size_t r = o; o = (o + bytes + 255) & ~(size_t)255; return r; };
  float* MEANS = (float*)(ws + alloc(98304u*4));
  bf16*  AHL   = (bf16*) (ws + alloc(589824u*2));    // PTOT*128 hi/lo A weights
  bf16*  WTT   = (bf16*) (ws + alloc(884736u*2));    // 2*384*1152 folded conv weights
  bf16*  WG0   = (bf16*) (ws + alloc(3538944u*2));
  bf16*  WSMALL= (bf16*) (ws + alloc(73728u*2));
  bf16*  HS    = (bf16*) (ws + alloc(1769472u*2));
  float* GBS   = (float*)(ws + alloc(294912u*4));
  float* Z0    = (float*)(ws + alloc(36864u*4));
  float* Z1    = (float*)(ws + alloc(73728u*4));
  float2* LNP  = (float2*)(ws + alloc(256u*8));
  float* STATS = (float*)(ws + alloc(16u*4));
  int*   FLAG  = (int*)  (ws + alloc(64u));
  float* SMALLF= (float*)(ws + alloc(31321u*4));
  float* MB    = (float*)(ws + alloc(9216u*4));
  float* BCOL  = (float*)(ws + alloc(64u*4));
  bf16*  ZPAD  = (bf16*) (ws + alloc(512u));

  float *BS0=SMALLF+0, *BS1=SMALLF+128, *BS2=SMALLF+256;
  float *BG0=SMALLF+384;
  float *W0=SMALLF+6576, *B0=SMALLF+31152;
  float *W1=SMALLF+31160, *B1=SMALLF+31288;
  float *W2=SMALLF+31304, *B2=SMALLF+31320;

  k_sniff<<<1, 256, 0, stream>>>((const unsigned*)x_main, FLAG, (float*)ZPAD);
  k_cvt_small<<<159, 256, 0, stream>>>(d_in[4], d_in[10], d_in[16], d_in[6], d_in[8],
      d_in[12], d_in[14], d_in[18], d_in[20], d_in[21], d_in[22], d_in[23], d_in[24],
      d_in[25], d_in[26], SMALLF, FLAG, MB);
  k_bcol<<<1, 256, 0, stream>>>(SMALLF, BCOL);
  k_mbeta<<<dim3(9,24), 256, 0, stream>>>(d_in[7], FLAG, W0, MB);
  k_wsm<<<36, 256, 0, stream>>>(MB, WSMALL);

  k_permW<128><<<dim3((3538944+255)/256),256, 0, stream>>>(d_in[5],  WG0,            3538944, FLAG);
  k_permW<128><<<dim3((9216+255)/256),   256, 0, stream>>>(d_in[11], WSMALL,           9216, FLAG);
  k_permW<128><<<dim3((9216+255)/256),   256, 0, stream>>>(d_in[13], WSMALL + 8*1152,  9216, FLAG);
  k_permW<128><<<dim3((18432+255)/256),  256, 0, stream>>>(d_in[17], WSMALL + 16*1152, 18432, FLAG);
  k_permW<128><<<dim3((18432+255)/256),  256, 0, stream>>>(d_in[19], WSMALL + 32*1152, 18432, FLAG);

  k_ln_partial<<<dim3(128,2), 256, 0, stream>>>(x_main, FLAG, LNP);
  k_ln_final<<<2, 128, 0, stream>>>(LNP, STATS);
  k_seg_means<<<dim3(64,2), 256, 0, stream>>>(f_sem, FLAG, segmap, MEANS);
  k_tt<<<dim3(216,2), 256, 0, stream>>>(d_in[3], d_in[9], d_in[15], FLAG, MEANS, WTT);
  k_A<<<PTOT, 192, 0, stream>>>(segmap, AHL);

  // G1: h = relu(conv3x3(sem, ws_l)) for all 3 layers -> HS (4608,384), folded-weight K=1152
  k_gemm<true, bf16><<<dim3(72,6), 256, 0, stream>>>(AHL, 128, 0, 128, WTT, 1152, (size_t)384*1152,
      BS0, BS1, BS2, 128, HS, 384, 0, 384, ZPAD);
  // merged small GEMMs (gamma1/beta1/gamma2/beta2/z0beta)
  k_gsmall<<<dim3(72,3), 256, 0, stream>>>(HS, WSMALL, BCOL, GBS, ZPAD);

  // layer-0: z0 = bias0 + z0beta + sum_c xn*(1+gamma)*w0   (gamma fused, never materialized)
  k_z0init<<<144, 256, 0, stream>>>(B0, GBS, Z0);
  k_gfuse<<<dim3(36,48), 256, 0, stream>>>(HS, WG0, BG0, x_main, FLAG, STATS, W0, Z0, ZPAD);
  k_spln<<<2, 256, 0, stream>>>(Z0, 18432, STATS + 4);

  k_F1<<<18, 256, 0, stream>>>(Z0, GBS, STATS + 4, W1, B1, Z1);
  k_ln_small<<<2, 256, 0, stream>>>(Z1, 36864, STATS + 8);
  k_F2<<<18, 256, 0, stream>>>(Z1, GBS, STATS + 8, W2, B2, d_out, FLAG);
}

// Round 6
// 597.873 us; speedup vs baseline: 1.1576x; 1.0398x over previous
//
#include <hip/hip_runtime.h>
#include <hip/hip_bf16.h>

typedef __hip_bfloat16 bf16;
typedef __bf16 v8bf __attribute__((ext_vector_type(8)));
typedef float v4f __attribute__((ext_vector_type(4)));

#define PB 2304
#define PTOT 4608

__device__ __forceinline__ float b2f(bf16 x){ return __bfloat162float(x); }
__device__ __forceinline__ bf16 f2b(float x){ return __float2bfloat16(x); }
__device__ __forceinline__ float softplus_f(float x){
  return fmaxf(x, 0.f) + log1pf(expf(-fabsf(x)));
}
__device__ __forceinline__ float LD(const void* src, size_t i, int fl){
  return fl ? ((const float*)src)[i] : b2f(((const bf16*)src)[i]);
}

// async global->LDS DMA, 16B per lane; LDS dest is wave-uniform base + lane*16
__device__ __forceinline__ void gload_lds16(const void* g, void* l){
  __builtin_amdgcn_global_load_lds(
      (const __attribute__((address_space(1))) void*)g,
      (__attribute__((address_space(3))) void*)l, 16, 0, 0);
}

// ---------- dtype sniffer (flag=1 if f32) + ZPAD zeroing ----------
__global__ __launch_bounds__(256) void k_sniff(const unsigned* __restrict__ x, int* __restrict__ flag,
                                               float* __restrict__ zp){
  int t = threadIdx.x;
  if (t < 128) zp[t] = 0.f;
  int cnt = 0;
  for (int i = t; i < 4096; i += 256){
    unsigned e = (x[i] >> 8) & 0x7F;
    if (e >= 0x38 && e <= 0x42) cnt++;
  }
  for (int off = 32; off; off >>= 1) cnt += __shfl_down(cnt, off, 64);
  __shared__ int sc[4];
  if ((t & 63) == 0) sc[t >> 6] = cnt;
  __syncthreads();
  if (t == 0) *flag = (sc[0]+sc[1]+sc[2]+sc[3] < 2048) ? 1 : 0;
}

// ---------- merged small-tensor canonicalization to f32 + MB zeroing ----------
__global__ __launch_bounds__(256) void k_cvt_small(
    const void* s4, const void* s10, const void* s16, const void* s6, const void* s8,
    const void* s12, const void* s14, const void* s18, const void* s20,
    const void* s21, const void* s22, const void* s23, const void* s24,
    const void* s25, const void* s26,
    float* __restrict__ dst, const int* __restrict__ flag, float* __restrict__ MB){
  int i = blockIdx.x*256 + threadIdx.x;
  if (i >= 40537) return;
  if (i >= 31321){ MB[i - 31321] = 0.f; return; }
  int fl = *flag;
  const void* src; size_t off;
  if      (i < 128)   { src = s4;  off = i; }
  else if (i < 256)   { src = s10; off = i - 128; }
  else if (i < 384)   { src = s16; off = i - 256; }
  else if (i < 3456)  { src = s6;  off = i - 384; }
  else if (i < 6528)  { src = s8;  off = i - 3456; }
  else if (i < 6536)  { src = s12; off = i - 6528; }
  else if (i < 6544)  { src = s14; off = i - 6536; }
  else if (i < 6560)  { src = s18; off = i - 6544; }
  else if (i < 6576)  { src = s20; off = i - 6560; }
  else if (i < 31152) { src = s21; off = i - 6576; }
  else if (i < 31160) { src = s22; off = i - 31152; }
  else if (i < 31288) { src = s23; off = i - 31160; }
  else if (i < 31304) { src = s24; off = i - 31288; }
  else if (i < 31320) { src = s25; off = i - 31304; }
  else                { src = s26; off = i - 31320; }
  dst[i] = LD(src, off, fl);
}

// ---------- BCOL[64]: per-column biases for the small GEMMs ----------
__global__ __launch_bounds__(256) void k_bcol(const float* __restrict__ SMALLF, float* __restrict__ BCOL){
  int t = threadIdx.x;
  const float* BG1 = SMALLF + 6528; const float* BB1 = SMALLF + 6536;
  const float* BG2 = SMALLF + 6544; const float* BB2 = SMALLF + 6560;
  const float* BB0 = SMALLF + 3456; const float* W0  = SMALLF + 6576;
  if (t < 8)       BCOL[t] = BG1[t];
  else if (t < 16) BCOL[t] = BB1[t-8];
  else if (t < 32) BCOL[t] = BG2[t-16];
  else if (t < 48) BCOL[t] = BB2[t-32];
  else if (t < 64) BCOL[t] = 0.f;
  float part[8] = {0,0,0,0,0,0,0,0};
  for (int c = t; c < 3072; c += 256){
    float bb = BB0[c];
    #pragma unroll
    for (int oc = 0; oc < 8; oc++) part[oc] += bb*W0[oc*3072 + c];
  }
  __shared__ float red[4][8];
  int wv = t >> 6, lane = t & 63;
  #pragma unroll
  for (int oc = 0; oc < 8; oc++){
    float v = part[oc];
    for (int off = 32; off; off >>= 1) v += __shfl_down(v, off, 64);
    if (lane == 0) red[wv][oc] = v;
  }
  __syncthreads();
  if (t < 8) BCOL[48 + t] = red[0][t] + red[1][t] + red[2][t] + red[3][t];
}

// ---------- M_beta[oc][j=dyx*128+ic] = sum_n wb0[n, ic, dyx] * w0[oc, n] ----------
__global__ __launch_bounds__(256) void k_mbeta(const void* __restrict__ wb0, const int* __restrict__ flag,
                                               const float* __restrict__ w0f, float* __restrict__ MB){
  int jb = blockIdx.x, nb = blockIdx.y, t = threadIdx.x;
  int fl = *flag;
  int jl = t & 127, nh = t >> 7;
  int j = jb*128 + jl;
  int src = jl*9 + jb;
  float acc[8] = {0,0,0,0,0,0,0,0};
  int n0 = nb*128 + nh*64;
  for (int i = 0; i < 64; i++){
    int n = n0 + i;
    float wv = LD(wb0, (size_t)n*1152 + src, fl);
    #pragma unroll
    for (int oc = 0; oc < 8; oc++) acc[oc] += wv*w0f[oc*3072 + n];
  }
  #pragma unroll
  for (int oc = 0; oc < 8; oc++) atomicAdd(&MB[oc*1152 + j], acc[oc]);
}

__global__ __launch_bounds__(256) void k_wsm(const float* __restrict__ MB, bf16* __restrict__ WSMALL){
  int i = blockIdx.x*256 + threadIdx.x;
  if (i >= 9216) return;
  float v = MB[i];
  bf16 hi = f2b(v);
  WSMALL[48*1152 + i] = hi;
  WSMALL[56*1152 + i] = f2b(v - b2f(hi));
}

// ---------- weight permute (oc, ic, 3,3) -> (oc, dyx, ic), bf16 out (small tensors only) ----------
template<int ICW>
__global__ __launch_bounds__(256) void k_permW(const void* __restrict__ src, bf16* __restrict__ dst,
                                               int total, const int* __restrict__ flag){
  int idx = blockIdx.x*256 + threadIdx.x;
  if (idx >= total) return;
  int oc = idx / (9*ICW);
  int rr = idx % (9*ICW);
  int dyx = rr / ICW, ic = rr % ICW;
  size_t si = (size_t)(oc*ICW + ic)*9 + dyx;
  dst[idx] = f2b(LD(src, si, *flag));
}

// ---------- coalesced oc-major permute for WG0: (oc, ic128, 3,3) -> (oc, dyx, ic), bf16 ----------
// per-oc src span (1152 elems) is contiguous -> read coalesced into LDS, write coalesced.
// Fixes the 9x read amplification of the strided k_permW path. 4 oc per block, grid 768.
__global__ __launch_bounds__(256) void k_permoc(const void* __restrict__ src, bf16* __restrict__ dst,
                                                const int* __restrict__ flag){
  __shared__ float lds[4608];
  int t = threadIdx.x;
  size_t base = (size_t)blockIdx.x*4608;
  int fl = *flag;
  for (int i = t; i < 4608; i += 256) lds[i] = LD(src, base + i, fl);
  __syncthreads();
  for (int i = t; i < 4608; i += 256){
    int ocl = i / 1152, r = i - ocl*1152;
    int dyx = r >> 7, ic = r & 127;
    dst[base + i] = f2b(lds[ocl*1152 + ic*9 + dyx]);
  }
}

// ---------- coalesced ws permute: (oc, ic768, 3,3) -> WSP[oc][dyx][ic] f32 ----------
// oc global = layer*128 + ocl. grid 384, one oc per block.
__global__ __launch_bounds__(256) void k_permws(const void* __restrict__ ws0, const void* __restrict__ ws1,
                                                const void* __restrict__ ws2, const int* __restrict__ flag,
                                                float* __restrict__ WSP){
  __shared__ float lds[6912];
  int t = threadIdx.x;
  int oc = blockIdx.x;
  int l = oc >> 7, ocl = oc & 127;
  const void* src = l == 0 ? ws0 : (l == 1 ? ws1 : ws2);
  int fl = *flag;
  for (int i = t; i < 6912; i += 256) lds[i] = LD(src, (size_t)ocl*6912 + i, fl);
  __syncthreads();
  float* o = WSP + (size_t)oc*6912;
  for (int i = t; i < 6912; i += 256){
    int dyx = i / 768, ic = i - dyx*768;
    o[i] = lds[ic*9 + dyx];
  }
}

// ---------- segment means over 24x24 downsampled segmap ----------
__global__ __launch_bounds__(256) void k_seg_means(const void* __restrict__ f_sem, const int* __restrict__ flag,
                                                   const int* __restrict__ segmap,
                                                   float* __restrict__ means){
  int s = blockIdx.x, b = blockIdx.y, t = threadIdx.x;
  int fl = *flag;
  __shared__ int sid[576];
  for (int i = t; i < 576; i += 256){
    int y = i / 24, x = i % 24;
    int v = segmap[b*336*336 + (y*14)*336 + x*14];
    sid[i] = min(max(v, 0), 63);
  }
  __syncthreads();
  float a0=0.f, a1=0.f, a2=0.f; int cnt = 0;
  for (int i = 0; i < 576; i++){
    if (sid[i] == s){
      cnt++;
      a0 += LD(f_sem, (size_t)(b*768 + t      )*576 + i, fl);
      a1 += LD(f_sem, (size_t)(b*768 + t + 256)*576 + i, fl);
      a2 += LD(f_sem, (size_t)(b*768 + t + 512)*576 + i, fl);
    }
  }
  float inv = cnt > 0 ? 1.f/(float)cnt : 0.f;
  float* o = means + (size_t)(b*64 + s)*768;
  o[t] = a0*inv; o[t+256] = a1*inv; o[t+512] = a2*inv;
}

// ---------- TT[b][oc][dyx][s] = sum_ic WSP[oc][dyx][ic] * means[b][s][ic] ----------
// Now reads the permuted WSP coalesced (was: stride-9 scattered raw ws reads).
__global__ __launch_bounds__(256) void k_tt(const float* __restrict__ WSP,
    const float* __restrict__ means, bf16* __restrict__ WTT){
  int bx = blockIdx.x;
  int dyx = bx / 24, ocb = bx % 24;
  int b = blockIdx.y, t = threadIdx.x;
  int ocg0 = ocb*16;
  __shared__ float wl[16][768];
  for (int ol = 0; ol < 16; ol++)
    for (int ic = t; ic < 768; ic += 256)
      wl[ol][ic] = WSP[(size_t)(ocg0 + ol)*6912 + (size_t)dyx*768 + ic];
  __syncthreads();
  int s = t & 63, og = t >> 6;
  const float* mr = means + ((size_t)b*64 + s)*768;
  float acc[4] = {0.f, 0.f, 0.f, 0.f};
  for (int ic = 0; ic < 768; ic += 4){
    float4 m = *reinterpret_cast<const float4*>(mr + ic);
    #pragma unroll
    for (int k = 0; k < 4; k++){
      const float* w = &wl[og + k*4][ic];
      acc[k] += m.x*w[0] + m.y*w[1] + m.z*w[2] + m.w*w[3];
    }
  }
  #pragma unroll
  for (int k = 0; k < 4; k++){
    bf16 h = f2b(acc[k]);
    size_t base = ((size_t)(b*384 + ocg0 + og + k*4))*1152 + (size_t)dyx*128 + s;
    WTT[base] = h;
    WTT[base + 64] = h;
  }
}

// ---------- per-pixel segment weights (antialiased bilinear 336->48), bf16 hi/lo out ----------
__global__ __launch_bounds__(192) void k_A(const int* __restrict__ segmap, bf16* __restrict__ AHL){
  int blk = blockIdx.x;
  int b = blk / PB, rem = blk % PB, yo = rem / 48, xo = rem % 48;
  __shared__ float accs[64];
  int t = threadIdx.x;
  if (t < 64) accs[t] = 0.f;
  __syncthreads();
  if (t < 169){
    int ty = t / 13, tx = t % 13;
    int jy = 7*yo - 3 + ty, jx = 7*xo - 3 + tx;
    if (jy >= 0 && jy < 336 && jx >= 0 && jx < 336){
      int wy = 7 - abs(ty - 6), wx = 7 - abs(tx - 6);
      int sv = segmap[b*336*336 + jy*336 + jx];
      sv = min(max(sv, 0), 63);
      atomicAdd(&accs[sv], (float)(wy*wx));
    }
  }
  int sumy = 0, sumx = 0;
  for (int k = 0; k < 13; k++){
    int jy = 7*yo - 3 + k; if (jy >= 0 && jy < 336) sumy += 7 - abs(k - 6);
    int jx = 7*xo - 3 + k; if (jx >= 0 && jx < 336) sumx += 7 - abs(k - 6);
  }
  __syncthreads();
  if (t < 64){
    float v = accs[t] / (float)(sumy*sumx);
    bf16 hi = f2b(v);
    AHL[(size_t)blk*128 + t] = hi;
    AHL[(size_t)blk*128 + 64 + t] = f2b(v - b2f(hi));
  }
}

// ---------- LN stats over x_main ----------
__global__ __launch_bounds__(256) void k_ln_partial(const void* __restrict__ x, const int* __restrict__ flag,
                                                    float2* __restrict__ part){
  int b = blockIdx.y, blk = blockIdx.x, t = threadIdx.x;
  int fl = *flag;
  size_t base = (size_t)b*7077888 + (size_t)blk*55296;
  float s = 0.f, sq = 0.f;
  for (int i = 0; i < 216; i++){
    float v = LD(x, base + t + i*256, fl);
    s += v; sq += v*v;
  }
  for (int off = 32; off; off >>= 1){ s += __shfl_down(s, off, 64); sq += __shfl_down(sq, off, 64); }
  __shared__ float ls[4], lq[4];
  int w = t >> 6, lane = t & 63;
  if (lane == 0){ ls[w] = s; lq[w] = sq; }
  __syncthreads();
  if (t == 0) part[b*128 + blk] = make_float2(ls[0]+ls[1]+ls[2]+ls[3], lq[0]+lq[1]+lq[2]+lq[3]);
}

__global__ void k_ln_final(const float2* __restrict__ part, float* __restrict__ stats){
  int b = blockIdx.x, t = threadIdx.x;
  float2 v = part[b*128 + t];
  float s = v.x, sq = v.y;
  for (int off = 32; off; off >>= 1){ s += __shfl_down(s, off, 64); sq += __shfl_down(sq, off, 64); }
  __shared__ float ls[2], lq[2];
  if ((t & 63) == 0){ ls[t>>6] = s; lq[t>>6] = sq; }
  __syncthreads();
  if (t == 0){
    s = ls[0]+ls[1]; sq = lq[0]+lq[1];
    const float N = 7077888.f;
    float mean = s/N; float var = sq/N - mean*mean; var = fmaxf(var, 0.f);
    stats[b*2] = mean; stats[b*2+1] = rsqrtf(var + 1e-12f);
  }
}

// ---------- softplus-in-place + LN stats (fused) ----------
__global__ __launch_bounds__(256) void k_spln(float* __restrict__ z, int cnt, float* __restrict__ stats){
  int b = blockIdx.x, t = threadIdx.x;
  float* p = z + (size_t)b*cnt;
  float s = 0.f, sq = 0.f;
  for (int i = t; i < cnt; i += 256){
    float v = softplus_f(p[i]);
    p[i] = v;
    s += v; sq += v*v;
  }
  for (int off = 32; off; off >>= 1){ s += __shfl_down(s, off, 64); sq += __shfl_down(sq, off, 64); }
  __shared__ float ls[4], lq[4];
  int w = t >> 6, lane = t & 63;
  if (lane == 0){ ls[w] = s; lq[w] = sq; }
  __syncthreads();
  if (t == 0){
    s = ls[0]+ls[1]+ls[2]+ls[3]; sq = lq[0]+lq[1]+lq[2]+lq[3];
    float mean = s/(float)cnt; float var = sq/(float)cnt - mean*mean; var = fmaxf(var, 0.f);
    stats[b*2] = mean; stats[b*2+1] = rsqrtf(var + 1e-12f);
  }
}

__global__ __launch_bounds__(256) void k_ln_small(const float* __restrict__ z, int cnt, float* __restrict__ stats){
  int b = blockIdx.x, t = threadIdx.x;
  const float* p = z + (size_t)b*cnt;
  float s = 0.f, sq = 0.f;
  for (int i = t; i < cnt; i += 256){ float v = p[i]; s += v; sq += v*v; }
  for (int off = 32; off; off >>= 1){ s += __shfl_down(s, off, 64); sq += __shfl_down(sq, off, 64); }
  __shared__ float ls[4], lq[4];
  int w = t >> 6, lane = t & 63;
  if (lane == 0){ ls[w] = s; lq[w] = sq; }
  __syncthreads();
  if (t == 0){
    s = ls[0]+ls[1]+ls[2]+ls[3]; sq = lq[0]+lq[1]+lq[2]+lq[3];
    float mean = s/(float)cnt; float var = sq/(float)cnt - mean*mean; var = fmaxf(var, 0.f);
    stats[b*2] = mean; stats[b*2+1] = rsqrtf(var + 1e-12f);
  }
}

// ---------- shared MFMA GEMM body (BK=64, 64x64 tile, 2-barrier structure) ----------
template<bool RELU, typename OT>
__device__ __forceinline__ void gemm_body(
    const bf16* __restrict__ Asrc, int AS, int acol, int ICW,
    const bf16* __restrict__ W, int K, size_t wbstride,
    const float* __restrict__ bp0, const float* __restrict__ bp1, const float* __restrict__ bp2, int seg,
    OT* __restrict__ out, int N, int ncb, int ldo, const bf16* __restrict__ zpad,
    int m0, int n0, bf16 (*Al)[64], bf16 (*Bl)[64])
{
  int t = threadIdx.x;
  int wv = t >> 6, lane = t & 63;
  int lr8 = lane >> 3, sseg = (lane & 7) ^ lr8;   // source 16B-seg (swizzled)
  int b = m0 >= PB ? 1 : 0;

  int ya[2], xa[2]; bool bv[2]; const bf16* wb[2];
  #pragma unroll
  for (int i = 0; i < 2; i++){
    int sp = (m0 - b*PB) + wv*16 + i*8 + lr8;
    ya[i] = sp / 48; xa[i] = sp % 48;
    int nrow = ncb + n0 + wv*16 + i*8 + lr8;
    bv[i] = nrow < N;
    wb[i] = W + (size_t)b*wbstride + (size_t)nrow*K + sseg*8;
  }

  int wm = (wv >> 1)*32, wn = (wv & 1)*32;
  int lrow = lane & 15, quad = lane >> 4;
  int sx = lrow & 7;
  int o0 = ((quad    ) ^ sx)*8;
  int o1 = ((quad + 4) ^ sx)*8;

  v4f acc00 = {0,0,0,0}, acc01 = {0,0,0,0}, acc10 = {0,0,0,0}, acc11 = {0,0,0,0};

  int dyx = 0, ic0 = 0;
  int ktn = K / 64;
  for (int kt = 0; kt < ktn; kt++){
    int dy = dyx/3 - 1, dx = dyx%3 - 1;
    #pragma unroll
    for (int i = 0; i < 2; i++){
      int ys = ya[i] + dy, xs = xa[i] + dx;
      const bf16* ga = (ys >= 0 && ys < 48 && xs >= 0 && xs < 48)
        ? Asrc + (size_t)(b*PB + ys*48 + xs)*AS + acol + ic0 + sseg*8 : zpad;
      gload_lds16(ga, &Al[wv*16 + i*8][0]);
      const bf16* gb = bv[i] ? wb[i] + kt*64 : zpad;
      gload_lds16(gb, &Bl[wv*16 + i*8][0]);
    }
    asm volatile("s_waitcnt vmcnt(0)" ::: "memory");
    __syncthreads();
    v8bf a00 = *reinterpret_cast<const v8bf*>(&Al[wm      + lrow][o0]);
    v8bf a10 = *reinterpret_cast<const v8bf*>(&Al[wm + 16 + lrow][o0]);
    v8bf a01 = *reinterpret_cast<const v8bf*>(&Al[wm      + lrow][o1]);
    v8bf a11 = *reinterpret_cast<const v8bf*>(&Al[wm + 16 + lrow][o1]);
    v8bf b00 = *reinterpret_cast<const v8bf*>(&Bl[wn      + lrow][o0]);
    v8bf b10 = *reinterpret_cast<const v8bf*>(&Bl[wn + 16 + lrow][o0]);
    v8bf b01 = *reinterpret_cast<const v8bf*>(&Bl[wn      + lrow][o1]);
    v8bf b11 = *reinterpret_cast<const v8bf*>(&Bl[wn + 16 + lrow][o1]);
    acc00 = __builtin_amdgcn_mfma_f32_16x16x32_bf16(a00, b00, acc00, 0, 0, 0);
    acc00 = __builtin_amdgcn_mfma_f32_16x16x32_bf16(a01, b01, acc00, 0, 0, 0);
    acc01 = __builtin_amdgcn_mfma_f32_16x16x32_bf16(a00, b10, acc01, 0, 0, 0);
    acc01 = __builtin_amdgcn_mfma_f32_16x16x32_bf16(a01, b11, acc01, 0, 0, 0);
    acc10 = __builtin_amdgcn_mfma_f32_16x16x32_bf16(a10, b00, acc10, 0, 0, 0);
    acc10 = __builtin_amdgcn_mfma_f32_16x16x32_bf16(a11, b01, acc10, 0, 0, 0);
    acc11 = __builtin_amdgcn_mfma_f32_16x16x32_bf16(a10, b10, acc11, 0, 0, 0);
    acc11 = __builtin_amdgcn_mfma_f32_16x16x32_bf16(a11, b11, acc11, 0, 0, 0);
    __syncthreads();
    ic0 += 64; if (ic0 == ICW){ ic0 = 0; dyx++; }
  }

  auto store_tile = [&](v4f a, int mi, int ni){
    int gcol = ncb + n0 + wn + ni*16 + lrow;
    if (gcol >= N) return;
    int sel = gcol / seg; sel = sel > 2 ? 2 : sel;
    const float* bp = sel == 0 ? bp0 : (sel == 1 ? bp1 : bp2);
    float bias = bp[gcol - sel*seg];
    int rowb = m0 + wm + mi*16 + quad*4;
    #pragma unroll
    for (int rg = 0; rg < 4; rg++){
      float v = a[rg] + bias;
      if (RELU) v = fmaxf(v, 0.f);
      if constexpr (sizeof(OT) == 2) out[(size_t)(rowb+rg)*ldo + (gcol - ncb)] = f2b(v);
      else                           out[(size_t)(rowb+rg)*ldo + (gcol - ncb)] = (OT)v;
    }
  };
  store_tile(acc00, 0, 0); store_tile(acc01, 0, 1);
  store_tile(acc10, 1, 0); store_tile(acc11, 1, 1);
}

template<bool RELU, typename OT>
__global__ __launch_bounds__(256) void k_gemm(
    const bf16* __restrict__ Asrc, int AS, int acol, int ICW,
    const bf16* __restrict__ W, int K, size_t wbstride,
    const float* __restrict__ bp0, const float* __restrict__ bp1, const float* __restrict__ bp2, int seg,
    OT* __restrict__ out, int N, int ncb, int ldo, const bf16* __restrict__ zpad)
{
  __shared__ __align__(16) bf16 Al[64][64];
  __shared__ __align__(16) bf16 Bl[64][64];
  gemm_body<RELU, OT>(Asrc, AS, acol, ICW, W, K, wbstride, bp0, bp1, bp2, seg,
                      out, N, ncb, ldo, zpad, blockIdx.x*64, blockIdx.y*64, Al, Bl);
}

// merged 3 small GEMMs: blockIdx.y selects {gamma1, beta1+gamma2, beta2+z0beta} config
__global__ __launch_bounds__(256) void k_gsmall(
    const bf16* __restrict__ HS, const bf16* __restrict__ WSMALL, const float* __restrict__ BCOL,
    float* __restrict__ GBS, const bf16* __restrict__ zpad)
{
  __shared__ __align__(16) bf16 Al[64][64];
  __shared__ __align__(16) bf16 Bl[64][64];
  int y = blockIdx.y;
  int acol = y == 0 ? 128 : (y == 1 ? 256 : 0);
  const bf16* W = WSMALL + (y == 0 ? 0 : (y == 1 ? 16*1152 : 48*1152));
  const float* bp = BCOL + (y == 0 ? 0 : (y == 1 ? 16 : 48));
  float* out = GBS + (y == 0 ? 0 : (y == 1 ? 16 : 48));
  int N = y == 1 ? 32 : 16;
  gemm_body<false, float>(HS, 384, acol, 128, W, 1152, 0, bp, bp, bp, 9999,
                          out, N, 0, 64, zpad, blockIdx.x*64, 0, Al, Bl);
}

// ---------- pure gamma GEMM (ablation split of k_gfuse): GAMMA[p][c] = im2col(HS)*WG0^T + bg0 ----------
// 128px x 128c tile, BK=64, grid (36,24). No epilogue register pressure (acc only).
__global__ __launch_bounds__(256, 4) void k_gg(
    const bf16* __restrict__ HS, const bf16* __restrict__ WG0, const float* __restrict__ BG0,
    bf16* __restrict__ GAMMA, const bf16* __restrict__ zpad)
{
  __shared__ __align__(16) bf16 Al[128][64];
  __shared__ __align__(16) bf16 Bl[128][64];
  int t = threadIdx.x;
  int m0 = blockIdx.x*128, n0 = blockIdx.y*128;
  int b = m0 >= PB ? 1 : 0;
  int wv = t >> 6, lane = t & 63;
  int lr8 = lane >> 3, sseg = (lane & 7) ^ lr8;
  int spbase = m0 - b*PB;

  int ya[4], xa[4];
  #pragma unroll
  for (int i = 0; i < 4; i++){
    int sp = spbase + wv*32 + i*8 + lr8;
    ya[i] = sp / 48; xa[i] = sp % 48;
  }
  const bf16* wgb = WG0 + (size_t)(n0 + wv*32 + lr8)*1152 + sseg*8;

  int wm = wv*32, lrow = lane & 15, quad = lane >> 4;
  int sx = lrow & 7;

  v4f acc[2][8];
  #pragma unroll
  for (int mi = 0; mi < 2; mi++)
    #pragma unroll
    for (int ni = 0; ni < 8; ni++) acc[mi][ni] = (v4f){0,0,0,0};

  for (int kt = 0; kt < 18; kt++){
    int dyx = kt >> 1, icr = (kt & 1) << 6;
    int dy = dyx/3 - 1, dx = dyx%3 - 1;
    #pragma unroll
    for (int i = 0; i < 4; i++){
      int ys = ya[i] + dy, xs = xa[i] + dx;
      const bf16* ga = (ys >= 0 && ys < 48 && xs >= 0 && xs < 48)
        ? HS + (size_t)(b*PB + ys*48 + xs)*384 + icr + sseg*8 : zpad;
      gload_lds16(ga, &Al[wv*32 + i*8][0]);
      gload_lds16(wgb + (size_t)(i*8)*1152 + dyx*128 + icr, &Bl[wv*32 + i*8][0]);
    }
    asm volatile("s_waitcnt vmcnt(0)" ::: "memory");
    __syncthreads();
    #pragma unroll
    for (int kh = 0; kh < 2; kh++){
      int oa = ((kh*4 + quad) ^ sx)*8;
      v8bf a0 = *reinterpret_cast<const v8bf*>(&Al[wm      + lrow][oa]);
      v8bf a1 = *reinterpret_cast<const v8bf*>(&Al[wm + 16 + lrow][oa]);
      #pragma unroll
      for (int ni = 0; ni < 8; ni++){
        v8bf bn = *reinterpret_cast<const v8bf*>(&Bl[ni*16 + lrow][oa]);
        acc[0][ni] = __builtin_amdgcn_mfma_f32_16x16x32_bf16(a0, bn, acc[0][ni], 0, 0, 0);
        acc[1][ni] = __builtin_amdgcn_mfma_f32_16x16x32_bf16(a1, bn, acc[1][ni], 0, 0, 0);
      }
    }
    __syncthreads();
  }

  #pragma unroll
  for (int mi = 0; mi < 2; mi++){
    int pr = m0 + wm + mi*16 + quad*4;
    #pragma unroll
    for (int ni = 0; ni < 8; ni++){
      int gc = n0 + ni*16 + lrow;
      float bg = BG0[gc];
      #pragma unroll
      for (int rg = 0; rg < 4; rg++)
        GAMMA[(size_t)(pr + rg)*3072 + gc] = f2b(acc[mi][ni][rg] + bg);
    }
  }
}

// ---------- z0 contraction: z0[p,oc] += sum_c xn[p,c]*(1+gamma[p,c])*w0[oc,c] ----------
// Streaming: x read coalesced (px per lane, c wave-uniform); gamma LDS-staged transposed.
// grid (72 px-blocks x 8 c-blocks), block 256 (64 px x 4 c-groups).
__global__ __launch_bounds__(256) void k_zc(
    const void* __restrict__ x, const bf16* __restrict__ GAMMA, const int* __restrict__ flag,
    const float* __restrict__ stats, const float* __restrict__ w0f, float* __restrict__ z0)
{
  __shared__ bf16 gmT[64][66];     // [c][px], pad 66 -> 2-way bank (free)
  __shared__ float w0l[8][64];
  __shared__ float red[4][64][8];
  int t = threadIdx.x;
  int p0 = blockIdx.x*64, cb = blockIdx.y;
  int b = p0 / PB;
  int spbase = p0 - b*PB;
  int fl = *flag;
  float mean = stats[b*2], rstd = stats[b*2+1];
  int px = t & 63, cg = t >> 6;
  int pxs = t >> 6, cl = t & 63;   // staging roles

  float acc[8] = {0,0,0,0,0,0,0,0};
  for (int ct = 0; ct < 6; ct++){
    int c0 = cb*384 + ct*64;
    #pragma unroll
    for (int k = 0; k < 16; k++){
      int p = pxs + k*4;
      gmT[cl][p] = GAMMA[(size_t)(p0 + p)*3072 + c0 + cl];
    }
    for (int i = t; i < 512; i += 256) w0l[i >> 6][i & 63] = w0f[(size_t)(i >> 6)*3072 + c0 + (i & 63)];
    __syncthreads();
    #pragma unroll
    for (int ci = 0; ci < 16; ci++){
      int c = cg*16 + ci;
      float xv = LD(x, ((size_t)(b*3072 + c0 + c))*2304 + spbase + px, fl);
      float xn = (xv - mean)*rstd;
      float tv = xn*(1.f + b2f(gmT[c][px]));
      #pragma unroll
      for (int oc = 0; oc < 8; oc++) acc[oc] += tv*w0l[oc][c];
    }
    __syncthreads();
  }
  #pragma unroll
  for (int oc = 0; oc < 8; oc++) red[cg][px][oc] = acc[oc];
  __syncthreads();
  #pragma unroll
  for (int j = 0; j < 2; j++){
    int idx = t + j*256;
    int p2 = idx >> 3, o2 = idx & 7;
    float s = red[0][p2][o2] + red[1][p2][o2] + red[2][p2][o2] + red[3][p2][o2];
    atomicAdd(&z0[(size_t)(p0 + p2)*8 + o2], s);
  }
}

// ---------- z0 init: bias0 + beta-contraction (GBS cols 48..55 hi + 56..63 lo) ----------
__global__ __launch_bounds__(256) void k_z0init(const float* __restrict__ b0f, const float* __restrict__ GBS,
                                                float* __restrict__ z0){
  int i = blockIdx.x*256 + threadIdx.x;
  if (i >= 36864) return;
  int p = i >> 3, oc = i & 7;
  z0[i] = b0f[oc] + GBS[(size_t)p*64 + 48 + oc] + GBS[(size_t)p*64 + 56 + oc];
}

__global__ __launch_bounds__(256) void k_F1(const float* __restrict__ z0, const float* __restrict__ GBS,
    const float* __restrict__ stats, const float* __restrict__ w1f, const float* __restrict__ b1f,
    float* __restrict__ z1){
  int p = blockIdx.x*256 + threadIdx.x;
  if (p >= PTOT) return;
  int b = p / PB;
  float mean = stats[b*2], rstd = stats[b*2+1];
  const float* zr = z0 + (size_t)p*8;
  const float* gr = GBS + (size_t)p*64;
  float yv[8];
  #pragma unroll
  for (int c = 0; c < 8; c++) yv[c] = (zr[c] - mean)*rstd*(1.f + gr[c]) + gr[8 + c];
  #pragma unroll
  for (int oc = 0; oc < 16; oc++){
    float s = b1f[oc];
    #pragma unroll
    for (int c = 0; c < 8; c++) s += yv[c]*w1f[oc*8 + c];
    z1[(size_t)p*16 + oc] = softplus_f(s);
  }
}

__global__ __launch_bounds__(256) void k_F2(const float* __restrict__ z1, const float* __restrict__ GBS,
    const float* __restrict__ stats, const float* __restrict__ w2f, const float* __restrict__ b2f,
    void* __restrict__ outp, const int* __restrict__ flag){
  int p = blockIdx.x*256 + threadIdx.x;
  if (p >= PTOT) return;
  int b = p / PB;
  float mean = stats[b*2], rstd = stats[b*2+1];
  const float* zr = z1 + (size_t)p*16;
  const float* gr = GBS + (size_t)p*64 + 16;
  float s = b2f[0];
  #pragma unroll
  for (int c = 0; c < 16; c++){
    float yv = (zr[c] - mean)*rstd*(1.f + gr[c]) + gr[16 + c];
    s += yv*w2f[c];
  }
  float r = softplus_f(s);
  if (*flag) ((float*)outp)[p] = r;
  else       ((bf16*)outp)[p] = f2b(r);
}

extern "C" void kernel_launch(void* const* d_in, const int* in_sizes, int n_in,
                              void* d_out, int out_size, void* d_ws, size_t ws_size,
                              hipStream_t stream){
  const void* x_main = d_in[0];
  const void* f_sem  = d_in[1];
  const int*  segmap = (const int*)d_in[2];

  char* ws = (char*)d_ws;
  size_t o = 0;
  auto alloc = [&](size_t bytes){ size_t r = o; o = (o + bytes + 255) & ~(size_t)255; return r; };
  float* MEANS = (float*)(ws + alloc(98304u*4));
  bf16*  AHL   = (bf16*) (ws + alloc(589824u*2));    // PTOT*128 hi/lo A weights
  bf16*  WTT   = (bf16*) (ws + alloc(884736u*2));    // 2*384*1152 folded conv weights
  bf16*  WG0   = (bf16*) (ws + alloc(3538944u*2));
  bf16*  WSMALL= (bf16*) (ws + alloc(73728u*2));
  bf16*  HS    = (bf16*) (ws + alloc(1769472u*2));
  float* WSP   = (float*)(ws + alloc(2654208u*4));   // 384*6912 permuted ws (f32)
  bf16*  GAMMA = (bf16*) (ws + alloc(14155776u*2));  // 4608*3072 gamma (layer 0)
  float* GBS   = (float*)(ws + alloc(294912u*4));
  float* Z0    = (float*)(ws + alloc(36864u*4));
  float* Z1    = (float*)(ws + alloc(73728u*4));
  float2* LNP  = (float2*)(ws + alloc(256u*8));
  float* STATS = (float*)(ws + alloc(16u*4));
  int*   FLAG  = (int*)  (ws + alloc(64u));
  float* SMALLF= (float*)(ws + alloc(31321u*4));
  float* MB    = (float*)(ws + alloc(9216u*4));
  float* BCOL  = (float*)(ws + alloc(64u*4));
  bf16*  ZPAD  = (bf16*) (ws + alloc(512u));

  float *BS0=SMALLF+0, *BS1=SMALLF+128, *BS2=SMALLF+256;
  float *BG0=SMALLF+384;
  float *W0=SMALLF+6576, *B0=SMALLF+31152;
  float *W1=SMALLF+31160, *B1=SMALLF+31288;
  float *W2=SMALLF+31304, *B2=SMALLF+31320;

  k_sniff<<<1, 256, 0, stream>>>((const unsigned*)x_main, FLAG, (float*)ZPAD);
  k_cvt_small<<<159, 256, 0, stream>>>(d_in[4], d_in[10], d_in[16], d_in[6], d_in[8],
      d_in[12], d_in[14], d_in[18], d_in[20], d_in[21], d_in[22], d_in[23], d_in[24],
      d_in[25], d_in[26], SMALLF, FLAG, MB);
  k_bcol<<<1, 256, 0, stream>>>(SMALLF, BCOL);
  k_mbeta<<<dim3(9,24), 256, 0, stream>>>(d_in[7], FLAG, W0, MB);
  k_wsm<<<36, 256, 0, stream>>>(MB, WSMALL);

  k_permoc<<<768, 256, 0, stream>>>(d_in[5], WG0, FLAG);          // coalesced WG0 permute
  k_permws<<<384, 256, 0, stream>>>(d_in[3], d_in[9], d_in[15], FLAG, WSP);
  k_permW<128><<<dim3((9216+255)/256),   256, 0, stream>>>(d_in[11], WSMALL,           9216, FLAG);
  k_permW<128><<<dim3((9216+255)/256),   256, 0, stream>>>(d_in[13], WSMALL + 8*1152,  9216, FLAG);
  k_permW<128><<<dim3((18432+255)/256),  256, 0, stream>>>(d_in[17], WSMALL + 16*1152, 18432, FLAG);
  k_permW<128><<<dim3((18432+255)/256),  256, 0, stream>>>(d_in[19], WSMALL + 32*1152, 18432, FLAG);

  k_ln_partial<<<dim3(128,2), 256, 0, stream>>>(x_main, FLAG, LNP);
  k_ln_final<<<2, 128, 0, stream>>>(LNP, STATS);
  k_seg_means<<<dim3(64,2), 256, 0, stream>>>(f_sem, FLAG, segmap, MEANS);
  k_tt<<<dim3(216,2), 256, 0, stream>>>(WSP, MEANS, WTT);
  k_A<<<PTOT, 192, 0, stream>>>(segmap, AHL);

  // G1: h = relu(conv3x3(sem, ws_l)) for all 3 layers -> HS (4608,384), folded-weight K=1152
  k_gemm<true, bf16><<<dim3(72,6), 256, 0, stream>>>(AHL, 128, 0, 128, WTT, 1152, (size_t)384*1152,
      BS0, BS1, BS2, 128, HS, 384, 0, 384, ZPAD);
  // merged small GEMMs (gamma1/beta1/gamma2/beta2/z0beta)
  k_gsmall<<<dim3(72,3), 256, 0, stream>>>(HS, WSMALL, BCOL, GBS, ZPAD);

  // layer-0 split: gamma GEMM -> GAMMA, then streaming z0 contraction
  k_z0init<<<144, 256, 0, stream>>>(B0, GBS, Z0);
  k_gg<<<dim3(36,24), 256, 0, stream>>>(HS, WG0, BG0, GAMMA, ZPAD);
  k_zc<<<dim3(72,8), 256, 0, stream>>>(x_main, GAMMA, FLAG, STATS, W0, Z0);
  k_spln<<<2, 256, 0, stream>>>(Z0, 18432, STATS + 4);

  k_F1<<<18, 256, 0, stream>>>(Z0, GBS, STATS + 4, W1, B1, Z1);
  k_ln_small<<<2, 256, 0, stream>>>(Z1, 36864, STATS + 8);
  k_F2<<<18, 256, 0, stream>>>(Z1, GBS, STATS + 8, W2, B2, d_out, FLAG);
}